// Round 9
// baseline (873.295 us; speedup 1.0000x reference)
//
#include <hip/hip_runtime.h>
#include <hip/hip_bf16.h>

#define NN 20000
#define EE 160000

typedef __attribute__((ext_vector_type(8))) short bf16x8;
typedef __attribute__((ext_vector_type(4))) float f32x4;

__device__ __forceinline__ unsigned short f2bf(float f) {
    unsigned int u = __float_as_uint(f);
    u += 0x7FFFu + ((u >> 16) & 1);   // RNE
    return (unsigned short)(u >> 16);
}
__device__ __forceinline__ float bf2f(short s) {
    return __uint_as_float(((unsigned int)(unsigned short)s) << 16);
}
__device__ __forceinline__ bf16x8 pack8(float4 a, float4 b) {
    bf16x8 r;
    r[0] = (short)f2bf(a.x); r[1] = (short)f2bf(a.y);
    r[2] = (short)f2bf(a.z); r[3] = (short)f2bf(a.w);
    r[4] = (short)f2bf(b.x); r[5] = (short)f2bf(b.y);
    r[6] = (short)f2bf(b.z); r[7] = (short)f2bf(b.w);
    return r;
}

// LDS map (shorts): [0,17408) sH (stride 136) / sW0 lives at 0 during layer0
// [17408,34816) sW2 (stride 136) / mode0 A-stage (stride 40)
// [34816,52224) sW1 (stride 136)
// sW0 strides: mode1 half=200 (25600), mode2=264 (33792), mode0=40, mode3=136
#define LDS_SHORTS 52224
#define SW2_OFF 17408
#define SW1_OFF 34816

// cooperative copy of 128 rows x nCols shorts into LDS with dstStride
__device__ __forceinline__ void stage_full(short* __restrict__ dst, int dstStride,
                                           const short* __restrict__ src, int srcRowLen,
                                           int colOff, int nCols, int tid)
{
    int nch = nCols >> 3;
    int total = 128 * nch;
    for (int i = tid; i < total; i += 256) {
        int r = i / nch, c = i - r * nch;
        *(bf16x8*)(dst + r * dstStride + c * 8) =
            *(const bf16x8*)(src + (size_t)r * srcRowLen + colOff + c * 8);
    }
}

// MFMA sweep: B from LDS (stride, col offset in shorts), 2 row-tiles x 8 col-tiles
__device__ __forceinline__ void mfma_sweep(f32x4 (&acc)[2][8], bf16x8 a0, bf16x8 a1,
                                           const short* sWb, int stride, int col, int lm)
{
#pragma unroll
    for (int ct = 0; ct < 8; ++ct) {
        bf16x8 b = *(const bf16x8*)(sWb + (ct * 16 + lm) * stride + col);
        acc[0][ct] = __builtin_amdgcn_mfma_f32_16x16x32_bf16(a0, b, acc[0][ct], 0, 0, 0);
        acc[1][ct] = __builtin_amdgcn_mfma_f32_16x16x32_bf16(a1, b, acc[1][ct], 0, 0, 0);
    }
}

__device__ __forceinline__ void zero_acc(f32x4 (&acc)[2][8]) {
#pragma unroll
    for (int i = 0; i < 2; ++i)
#pragma unroll
        for (int j = 0; j < 8; ++j) acc[i][j] = (f32x4)(0.f);
}

// park acc -> sH (stride 136) as bf16 with bias+relu (wave-private rows)
__device__ __forceinline__ void park(const f32x4 (&acc)[2][8], const float* __restrict__ bias,
                                     short* __restrict__ sH, int w32, int lm, int lq)
{
#pragma unroll
    for (int ct = 0; ct < 8; ++ct) {
        float bb = bias[ct * 16 + lm];
#pragma unroll
        for (int rt = 0; rt < 2; ++rt) {
            int rbase = w32 + rt * 16 + lq * 4;
#pragma unroll
            for (int reg = 0; reg < 4; ++reg) {
                float v = fmaxf(acc[rt][ct][reg] + bb, 0.f);
                sH[(rbase + reg) * 136 + ct * 16 + lm] = (short)f2bf(v);
            }
        }
    }
}

// modes: 0 encoder; 1 edge (sorted); 2 node; 3 decoder
__global__ __launch_bounds__(256, 1) void gnn_mlp(
    const short* __restrict__ Wt0, int Kpad0,
    const short* __restrict__ Wt1, const short* __restrict__ Wt2,
    const float* __restrict__ b0, const float* __restrict__ b1, const float* __restrict__ b2,
    const float* __restrict__ g, const float* __restrict__ be,
    const float* __restrict__ A0f, int K0,          // mode0: src; mode3: dec_W2 [128x3]
    const short* __restrict__ nfb,
    const float* __restrict__ eff,
    const float* __restrict__ aggf,
    const int* __restrict__ eList,
    const int* __restrict__ senders, const int* __restrict__ receivers,
    float* __restrict__ outF, short* __restrict__ outB,
    float* __restrict__ aggOut,
    float* __restrict__ decOut,
    int M, int mode, int resid)
{
    __shared__ short smem[LDS_SHORTS];
    __shared__ int sEdge[128], sRcv[128], sSnd[128];
    const int tid = threadIdx.x;
    const int lane = tid & 63;
    const int w = tid >> 6;
    const int lm = lane & 15;
    const int lq = lane >> 4;
    const int w32 = w * 32;
    const int m0 = blockIdx.x * 128;
    short* const sH  = smem;
    short* const sW1 = smem + SW1_OFF;
    short* const sW2 = smem + SW2_OFF;

    if (mode == 1 && tid < 128) {
        int slot = m0 + tid;
        int e = eList ? eList[slot] : slot;
        sEdge[tid] = e;
        sRcv[tid] = receivers[e];
        sSnd[tid] = senders[e];
    }
    // no barrier yet: sEdge consumed only after the B1 barrier below

    f32x4 acc[2][8];
    zero_acc(acc);

    // ---- initial staging: sW0 (first half / whole) + sW1 ----
    if (mode == 0)      stage_full(smem, 40, Wt0, Kpad0, 0, 32, tid);
    else if (mode == 1) stage_full(smem, 200, Wt0, Kpad0, 0, 192, tid);
    else if (mode == 2) stage_full(smem, 264, Wt0, Kpad0, 0, 256, tid);
    else                stage_full(smem, 136, Wt0, Kpad0, 0, 128, tid);
    stage_full(sW1, 136, Wt1, 128, 0, 128, tid);

    if (mode == 0) {
        // wave-private A stage (32 rows x 32 k, zero-padded) into SW2 region, stride 40
        short* sA = sW2;
#pragma unroll
        for (int i = 0; i < 16; ++i) {
            int flat = lane + i * 64;
            int r = flat >> 5, k = flat & 31;
            int row = m0 + w32 + r;
            float v = (k < K0 && row < M) ? A0f[(size_t)row * K0 + k] : 0.f;
            sA[(w32 + r) * 40 + k] = (short)f2bf(v);
        }
    }
    __syncthreads();   // B1: sW0(+half0)/sW1 staged, sEdge ready

    // -------- layer 0 (barrier-free K loops) --------
    if (mode == 0) {
        short* sA = sW2;
        bf16x8 a0 = *(const bf16x8*)&sA[(w32 + lm) * 40 + lq * 8];
        bf16x8 a1 = *(const bf16x8*)&sA[(w32 + 16 + lm) * 40 + lq * 8];
        mfma_sweep(acc, a0, a1, smem, 40, lq * 8, lm);
    } else if (mode == 1) {
        const short* pS0 = nfb + (size_t)sSnd[w32 + lm] * 128;
        const short* pS1 = nfb + (size_t)sSnd[w32 + 16 + lm] * 128;
        const short* pR0 = nfb + (size_t)sRcv[w32 + lm] * 128;
        const short* pR1 = nfb + (size_t)sRcv[w32 + 16 + lm] * 128;
        const float* pE0 = eff + (size_t)sEdge[w32 + lm] * 128;
        const float* pE1 = eff + (size_t)sEdge[w32 + 16 + lm] * 128;
        // prefetch ALL layer-0 A fragments (both halves) up front
        bf16x8 fS0[4], fS1[4], fRa0[2], fRa1[2], fRb0[2], fRb1[2];
        float4 g0[4][2], g1[4][2];
#pragma unroll
        for (int c = 0; c < 4; ++c) {
            int kb = c * 32 + lq * 8;
            fS0[c] = *(const bf16x8*)(pS0 + kb);
            fS1[c] = *(const bf16x8*)(pS1 + kb);
        }
#pragma unroll
        for (int c = 0; c < 2; ++c) {
            int kb = c * 32 + lq * 8;
            fRa0[c] = *(const bf16x8*)(pR0 + kb);
            fRa1[c] = *(const bf16x8*)(pR1 + kb);
            fRb0[c] = *(const bf16x8*)(pR0 + 64 + kb);
            fRb1[c] = *(const bf16x8*)(pR1 + 64 + kb);
        }
#pragma unroll
        for (int c = 0; c < 4; ++c) {
            int kb = c * 32 + lq * 8;
            g0[c][0] = *(const float4*)(pE0 + kb); g0[c][1] = *(const float4*)(pE0 + kb + 4);
            g1[c][0] = *(const float4*)(pE1 + kb); g1[c][1] = *(const float4*)(pE1 + kb + 4);
        }
        // half 0: global k 0..191 (seg0 chunks 0-3, seg1 chunks 0-1)
#pragma unroll
        for (int c = 0; c < 4; ++c)
            mfma_sweep(acc, fS0[c], fS1[c], smem, 200, c * 32 + lq * 8, lm);
#pragma unroll
        for (int c = 0; c < 2; ++c)
            mfma_sweep(acc, fRa0[c], fRa1[c], smem, 200, 128 + c * 32 + lq * 8, lm);
        __syncthreads();
        stage_full(smem, 200, Wt0, Kpad0, 192, 192, tid);
        __syncthreads();
        // half 1: global k 192..383 (seg1 chunks 2-3, seg2 chunks 0-3)
#pragma unroll
        for (int c = 0; c < 2; ++c)
            mfma_sweep(acc, fRb0[c], fRb1[c], smem, 200, c * 32 + lq * 8, lm);
#pragma unroll
        for (int c = 0; c < 4; ++c) {
            bf16x8 a0 = pack8(g0[c][0], g0[c][1]);
            bf16x8 a1 = pack8(g1[c][0], g1[c][1]);
            mfma_sweep(acc, a0, a1, smem, 200, 64 + c * 32 + lq * 8, lm);
        }
    } else if (mode == 2) {
        int r0 = min(m0 + w32 + lm, M - 1), r1 = min(m0 + w32 + 16 + lm, M - 1);
        bf16x8 fN0[4], fN1[4];
        float4 g0[4][2], g1[4][2];
#pragma unroll
        for (int c = 0; c < 4; ++c) {
            int kb = c * 32 + lq * 8;
            fN0[c] = *(const bf16x8*)(nfb + (size_t)r0 * 128 + kb);
            fN1[c] = *(const bf16x8*)(nfb + (size_t)r1 * 128 + kb);
            g0[c][0] = *(const float4*)(aggf + (size_t)r0 * 128 + kb);
            g0[c][1] = *(const float4*)(aggf + (size_t)r0 * 128 + kb + 4);
            g1[c][0] = *(const float4*)(aggf + (size_t)r1 * 128 + kb);
            g1[c][1] = *(const float4*)(aggf + (size_t)r1 * 128 + kb + 4);
        }
#pragma unroll
        for (int c = 0; c < 4; ++c)
            mfma_sweep(acc, fN0[c], fN1[c], smem, 264, c * 32 + lq * 8, lm);
#pragma unroll
        for (int c = 0; c < 4; ++c) {
            bf16x8 a0 = pack8(g0[c][0], g0[c][1]);
            bf16x8 a1 = pack8(g1[c][0], g1[c][1]);
            mfma_sweep(acc, a0, a1, smem, 264, 128 + c * 32 + lq * 8, lm);
        }
    } else {  // mode 3
        int r0 = min(m0 + w32 + lm, M - 1), r1 = min(m0 + w32 + 16 + lm, M - 1);
#pragma unroll
        for (int c = 0; c < 4; ++c) {
            int kb = c * 32 + lq * 8;
            bf16x8 a0 = *(const bf16x8*)(nfb + (size_t)r0 * 128 + kb);
            bf16x8 a1 = *(const bf16x8*)(nfb + (size_t)r1 * 128 + kb);
            mfma_sweep(acc, a0, a1, smem, 136, c * 32 + lq * 8, lm);
        }
    }

    __syncthreads();   // B2: all waves done reading sW0 region
    park(acc, b0, sH, w32, lm, lq);                  // h1 -> sH (overlays dead sW0)
    if (Wt2) stage_full(sW2, 136, Wt2, 128, 0, 128, tid);
    __syncthreads();   // B3: sW2 staged

    // -------- layer 1 (barrier-free) --------
    zero_acc(acc);
#pragma unroll
    for (int c = 0; c < 4; ++c) {
        int kb = c * 32 + lq * 8;
        bf16x8 a0 = *(const bf16x8*)&sH[(w32 + lm) * 136 + kb];
        bf16x8 a1 = *(const bf16x8*)&sH[(w32 + 16 + lm) * 136 + kb];
        mfma_sweep(acc, a0, a1, sW1, 136, kb, lm);
    }
    park(acc, b1, sH, w32, lm, lq);                  // h2 -> sH (own rows)

    // -------- decoder tail --------
    if (mode == 3) {
#pragma unroll
        for (int t = 0; t < 2; ++t) {
            int idx = t * 64 + lane;
            if (idx < 96) {
                int r = idx / 3, o = idx - r * 3;
                int row = m0 + w32 + r;
                if (row < M) {
                    float s = b2[o];
#pragma unroll
                    for (int kk = 0; kk < 16; ++kk) {
                        bf16x8 h8 = *(const bf16x8*)&sH[(w32 + r) * 136 + kk * 8];
#pragma unroll
                        for (int j = 0; j < 8; ++j)
                            s += bf2f(h8[j]) * A0f[(kk * 8 + j) * 3 + o];
                    }
                    decOut[(size_t)row * 3 + o] = s;
                }
            }
        }
        return;
    }

    // -------- layer 2 (barrier-free) --------
    zero_acc(acc);
#pragma unroll
    for (int c = 0; c < 4; ++c) {
        int kb = c * 32 + lq * 8;
        bf16x8 a0 = *(const bf16x8*)&sH[(w32 + lm) * 136 + kb];
        bf16x8 a1 = *(const bf16x8*)&sH[(w32 + 16 + lm) * 136 + kb];
        mfma_sweep(acc, a0, a1, sW2, 136, kb, lm);
    }

    // -------- epilogue --------
    float g_[8], be_[8], b2_[8];
#pragma unroll
    for (int ct = 0; ct < 8; ++ct) {
        g_[ct] = g[ct * 16 + lm]; be_[ct] = be[ct * 16 + lm]; b2_[ct] = b2[ct * 16 + lm];
    }

    if (mode == 1) {
#pragma unroll
        for (int rt = 0; rt < 2; ++rt) {
            float run[8];
            int curRcv = -1;
#pragma unroll
            for (int reg = 0; reg < 4; ++reg) {
                int rloc = w32 + rt * 16 + lq * 4 + reg;
                float v[8];
                float s = 0.f;
#pragma unroll
                for (int ct = 0; ct < 8; ++ct) { v[ct] = acc[rt][ct][reg] + b2_[ct]; s += v[ct]; }
                s += __shfl_xor(s, 1); s += __shfl_xor(s, 2);
                s += __shfl_xor(s, 4); s += __shfl_xor(s, 8);
                float mu = s * (1.f / 128.f);
                float q = 0.f;
#pragma unroll
                for (int ct = 0; ct < 8; ++ct) { v[ct] -= mu; q += v[ct] * v[ct]; }
                q += __shfl_xor(q, 1); q += __shfl_xor(q, 2);
                q += __shfl_xor(q, 4); q += __shfl_xor(q, 8);
                float rs = rsqrtf(q * (1.f / 128.f) + 1e-5f);
                int e = sEdge[rloc];
                int rcv = sRcv[rloc];
                float o[8];
#pragma unroll
                for (int ct = 0; ct < 8; ++ct) {
                    o[ct] = v[ct] * rs * g_[ct] + be_[ct];
                    size_t gi = (size_t)e * 128 + ct * 16 + lm;
                    outF[gi] += o[ct];
                }
                if (rcv != curRcv) {
                    if (curRcv >= 0) {
#pragma unroll
                        for (int ct = 0; ct < 8; ++ct)
                            atomicAdd(aggOut + (size_t)curRcv * 128 + ct * 16 + lm, run[ct]);
                    }
                    curRcv = rcv;
#pragma unroll
                    for (int ct = 0; ct < 8; ++ct) run[ct] = o[ct];
                } else {
#pragma unroll
                    for (int ct = 0; ct < 8; ++ct) run[ct] += o[ct];
                }
            }
            if (curRcv >= 0) {
#pragma unroll
                for (int ct = 0; ct < 8; ++ct)
                    atomicAdd(aggOut + (size_t)curRcv * 128 + ct * 16 + lm, run[ct]);
            }
        }
    } else {
#pragma unroll
        for (int rt = 0; rt < 2; ++rt) {
#pragma unroll
            for (int reg = 0; reg < 4; ++reg) {
                int row = m0 + w32 + rt * 16 + lq * 4 + reg;
                float v[8];
                float s = 0.f;
#pragma unroll
                for (int ct = 0; ct < 8; ++ct) { v[ct] = acc[rt][ct][reg] + b2_[ct]; s += v[ct]; }
                s += __shfl_xor(s, 1); s += __shfl_xor(s, 2);
                s += __shfl_xor(s, 4); s += __shfl_xor(s, 8);
                float mu = s * (1.f / 128.f);
                float q = 0.f;
#pragma unroll
                for (int ct = 0; ct < 8; ++ct) { v[ct] -= mu; q += v[ct] * v[ct]; }
                q += __shfl_xor(q, 1); q += __shfl_xor(q, 2);
                q += __shfl_xor(q, 4); q += __shfl_xor(q, 8);
                float rs = rsqrtf(q * (1.f / 128.f) + 1e-5f);
                if (row < M) {
#pragma unroll
                    for (int ct = 0; ct < 8; ++ct) {
                        float o = v[ct] * rs * g_[ct] + be_[ct];
                        size_t gi = (size_t)row * 128 + ct * 16 + lm;
                        if (resid) {
                            float ns = outF[gi] + o;
                            outF[gi] = ns;
                            if (outB) outB[gi] = (short)f2bf(ns);
                        } else {
                            outF[gi] = o;
                            if (outB) outB[gi] = (short)f2bf(o);
                        }
                    }
                }
            }
        }
    }
}

// ---------------------------------------------------------------------------
__global__ void zero_i(int* __restrict__ p, int n)
{
    int i = blockIdx.x * 256 + threadIdx.x;
    if (i < n) p[i] = 0;
}
__global__ void csr_count(const int* __restrict__ recv, int* __restrict__ cnt, int E)
{
    int i = blockIdx.x * 256 + threadIdx.x;
    if (i < E) atomicAdd(&cnt[recv[i]], 1);
}
__global__ __launch_bounds__(256) void csr_scan(const int* __restrict__ cnt,
                                                int* __restrict__ cursor, int N)
{
    __shared__ int ssum[257];
    const int tid = threadIdx.x;
    const int per = (N + 255) / 256;
    const int lo = tid * per, hi = min(lo + per, N);
    int s = 0;
    for (int i = lo; i < hi; ++i) s += cnt[i];
    ssum[tid] = s;
    __syncthreads();
    if (tid == 0) {
        int run = 0;
        for (int i = 0; i < 256; ++i) { int t = ssum[i]; ssum[i] = run; run += t; }
        ssum[256] = run;
    }
    __syncthreads();
    int run = ssum[tid];
    for (int i = lo; i < hi; ++i) { int c = cnt[i]; cursor[i] = run; run += c; }
}
__global__ void csr_fill(const int* __restrict__ recv, int* __restrict__ cursor,
                         int* __restrict__ eList, int E)
{
    int i = blockIdx.x * 256 + threadIdx.x;
    if (i < E) {
        int pos = atomicAdd(&cursor[recv[i]], 1);
        eList[pos] = i;
    }
}

// ---------------------------------------------------------------------------
struct WtPrep { const float* src; int K; int Kpad; int dstOff; };
struct WtPrepAll { WtPrep m[26]; };

__global__ void wt_prep_kernel(WtPrepAll all, short* __restrict__ dst)
{
    const WtPrep p = all.m[blockIdx.y];
    int total = 128 * p.Kpad;
    int idx = blockIdx.x * 256 + threadIdx.x;
    if (idx >= total) return;
    int n = idx / p.Kpad, k = idx - n * p.Kpad;
    float v = (k < p.K) ? p.src[(size_t)k * 128 + n] : 0.f;
    dst[p.dstOff + idx] = (short)f2bf(v);
}

__global__ void zero_kernel(float4* __restrict__ p, long n4)
{
    long i = (long)blockIdx.x * blockDim.x + threadIdx.x;
    if (i < n4) p[i] = make_float4(0.f, 0.f, 0.f, 0.f);
}

// ---------------------------------------------------------------------------
extern "C" void kernel_launch(void* const* d_in, const int* in_sizes, int n_in,
                              void* d_out, int out_size, void* d_ws, size_t ws_size,
                              hipStream_t stream)
{
    const float* node_x   = (const float*)d_in[0];
    const float* edge_x   = (const float*)d_in[1];
    const float* enc_n_W0 = (const float*)d_in[2];
    const float* enc_n_b0 = (const float*)d_in[3];
    const float* enc_n_W1 = (const float*)d_in[4];
    const float* enc_n_b1 = (const float*)d_in[5];
    const float* enc_n_W2 = (const float*)d_in[6];
    const float* enc_n_b2 = (const float*)d_in[7];
    const float* enc_n_g  = (const float*)d_in[8];
    const float* enc_n_be = (const float*)d_in[9];
    const float* enc_e_W0 = (const float*)d_in[10];
    const float* enc_e_b0 = (const float*)d_in[11];
    const float* enc_e_W1 = (const float*)d_in[12];
    const float* enc_e_b1 = (const float*)d_in[13];
    const float* enc_e_W2 = (const float*)d_in[14];
    const float* enc_e_b2 = (const float*)d_in[15];
    const float* enc_e_g  = (const float*)d_in[16];
    const float* enc_e_be = (const float*)d_in[17];
    const float* gnb_e_W0 = (const float*)d_in[18];
    const float* gnb_e_b0 = (const float*)d_in[19];
    const float* gnb_e_W1 = (const float*)d_in[20];
    const float* gnb_e_b1 = (const float*)d_in[21];
    const float* gnb_e_W2 = (const float*)d_in[22];
    const float* gnb_e_b2 = (const float*)d_in[23];
    const float* gnb_e_g  = (const float*)d_in[24];
    const float* gnb_e_be = (const float*)d_in[25];
    const float* gnb_n_W0 = (const float*)d_in[26];
    const float* gnb_n_b0 = (const float*)d_in[27];
    const float* gnb_n_W1 = (const float*)d_in[28];
    const float* gnb_n_b1 = (const float*)d_in[29];
    const float* gnb_n_W2 = (const float*)d_in[30];
    const float* gnb_n_b2 = (const float*)d_in[31];
    const float* gnb_n_g  = (const float*)d_in[32];
    const float* gnb_n_be = (const float*)d_in[33];
    const float* dec_W0   = (const float*)d_in[34];
    const float* dec_b0   = (const float*)d_in[35];
    const float* dec_W1   = (const float*)d_in[36];
    const float* dec_b1   = (const float*)d_in[37];
    const float* dec_W2   = (const float*)d_in[38];
    const float* dec_b2   = (const float*)d_in[39];
    const int*   senders  = (const int*)d_in[40];
    const int*   receivers= (const int*)d_in[41];
    float* out = (float*)d_out;

    const int N = NN, E = EE;
    const int WT_TOTAL = (32 + 128 + 128 + 32 + 128 + 128 + 3 * (384 + 128 + 128 + 256 + 128 + 128)
                          + 128 + 128) * 128;

    // ---- workspace layout: identical to round 6/8 (109.26 MB, known-good) ----
    float* nf   = (float*)d_ws;
    float* agg  = nf + (size_t)N * 128;
    float* ef   = agg + (size_t)N * 128;
    short* nfbf = (short*)(ef + (size_t)E * 128);
    short* wt   = nfbf + (size_t)N * 128;
    int*   eList = (int*)(wt + WT_TOTAL);
    size_t need_sorted = (size_t)((char*)(eList + E) - (char*)d_ws);
    int* cnt    = (int*)agg;
    int* cursor = cnt + N;

    const bool useSorted = (ws_size >= need_sorted);
    const int* eL = useSorted ? eList : nullptr;

    WtPrepAll tbl;
    int nMat = 0, off = 0;
    int o_encn[3], o_ence[3], o_ge0[3], o_ge1[3], o_ge2[3], o_gn0[3], o_gn1[3], o_gn2[3], o_dec[2];
    auto add = [&](const float* src, int K, int Kpad) {
        tbl.m[nMat].src = src; tbl.m[nMat].K = K; tbl.m[nMat].Kpad = Kpad;
        tbl.m[nMat].dstOff = off;
        int r = off; off += 128 * Kpad; ++nMat; return r;
    };
    o_encn[0] = add(enc_n_W0, 12, 32);
    o_encn[1] = add(enc_n_W1, 128, 128);
    o_encn[2] = add(enc_n_W2, 128, 128);
    o_ence[0] = add(enc_e_W0, 7, 32);
    o_ence[1] = add(enc_e_W1, 128, 128);
    o_ence[2] = add(enc_e_W2, 128, 128);
    for (int s = 0; s < 3; ++s) {
        o_ge0[s] = add(gnb_e_W0 + (size_t)s * 384 * 128, 384, 384);
        o_ge1[s] = add(gnb_e_W1 + (size_t)s * 128 * 128, 128, 128);
        o_ge2[s] = add(gnb_e_W2 + (size_t)s * 128 * 128, 128, 128);
        o_gn0[s] = add(gnb_n_W0 + (size_t)s * 256 * 128, 256, 256);
        o_gn1[s] = add(gnb_n_W1 + (size_t)s * 128 * 128, 128, 128);
        o_gn2[s] = add(gnb_n_W2 + (size_t)s * 128 * 128, 128, 128);
    }
    o_dec[0] = add(dec_W0, 128, 128);
    o_dec[1] = add(dec_W1, 128, 128);

    wt_prep_kernel<<<dim3(192, 26), 256, 0, stream>>>(tbl, wt);

    if (useSorted) {
        zero_i<<<dim3((N + 255) / 256), 256, 0, stream>>>(cnt, N);
        csr_count<<<dim3((E + 255) / 256), 256, 0, stream>>>(receivers, cnt, E);
        csr_scan<<<dim3(1), 256, 0, stream>>>(cnt, cursor, N);
        csr_fill<<<dim3((E + 255) / 256), 256, 0, stream>>>(receivers, cursor, eList, E);
    }

    const dim3 gN((N + 127) / 128), gE(E / 128);

    // ---- encoders ----
    gnn_mlp<<<gN, 256, 0, stream>>>(wt + o_encn[0], 32, wt + o_encn[1], wt + o_encn[2],
        enc_n_b0, enc_n_b1, enc_n_b2, enc_n_g, enc_n_be,
        node_x, 12, nullptr, nullptr, nullptr, nullptr, nullptr, nullptr,
        nf, nfbf, nullptr, nullptr, N, 0, 0);
    gnn_mlp<<<gE, 256, 0, stream>>>(wt + o_ence[0], 32, wt + o_ence[1], wt + o_ence[2],
        enc_e_b0, enc_e_b1, enc_e_b2, enc_e_g, enc_e_be,
        edge_x, 7, nullptr, nullptr, nullptr, nullptr, nullptr, nullptr,
        ef, nullptr, nullptr, nullptr, E, 0, 0);

    // ---- 3 message-passing steps ----
    for (int s = 0; s < 3; ++s) {
        const float* eb0 = gnb_e_b0 + (size_t)s * 128;
        const float* eb1 = gnb_e_b1 + (size_t)s * 128;
        const float* eb2 = gnb_e_b2 + (size_t)s * 128;
        const float* eg  = gnb_e_g  + (size_t)s * 128;
        const float* ebe = gnb_e_be + (size_t)s * 128;
        const float* nb0 = gnb_n_b0 + (size_t)s * 128;
        const float* nb1 = gnb_n_b1 + (size_t)s * 128;
        const float* nb2 = gnb_n_b2 + (size_t)s * 128;
        const float* ng  = gnb_n_g  + (size_t)s * 128;
        const float* nbe = gnb_n_be + (size_t)s * 128;

        zero_kernel<<<dim3((N * 32 + 255) / 256), 256, 0, stream>>>((float4*)agg, (long)N * 32);
        gnn_mlp<<<gE, 256, 0, stream>>>(wt + o_ge0[s], 384, wt + o_ge1[s], wt + o_ge2[s],
            eb0, eb1, eb2, eg, ebe,
            nullptr, 0, nfbf, ef, nullptr, eL, senders, receivers,
            ef, nullptr, agg, nullptr, E, 1, 1);
        gnn_mlp<<<gN, 256, 0, stream>>>(wt + o_gn0[s], 256, wt + o_gn1[s], wt + o_gn2[s],
            nb0, nb1, nb2, ng, nbe,
            nullptr, 0, nfbf, nullptr, agg, nullptr, nullptr, nullptr,
            nf, nfbf, nullptr, nullptr, N, 2, 1);
    }

    // ---- decoder ----
    gnn_mlp<<<gN, 256, 0, stream>>>(wt + o_dec[0], 128, wt + o_dec[1], nullptr,
        dec_b0, dec_b1, dec_b2, nullptr, nullptr,
        dec_W2, 0, nfbf, nullptr, nullptr, nullptr, nullptr, nullptr,
        nullptr, nullptr, nullptr, out, N, 3, 0);
}

// Round 10
// 763.046 us; speedup vs baseline: 1.1445x; 1.1445x over previous
//
#include <hip/hip_runtime.h>
#include <hip/hip_bf16.h>

#define NN 20000
#define EE 160000

typedef __attribute__((ext_vector_type(8))) short bf16x8;
typedef __attribute__((ext_vector_type(4))) float f32x4;

__device__ __forceinline__ unsigned short f2bf(float f) {
    unsigned int u = __float_as_uint(f);
    u += 0x7FFFu + ((u >> 16) & 1);   // RNE
    return (unsigned short)(u >> 16);
}
__device__ __forceinline__ float bf2f(short s) {
    return __uint_as_float(((unsigned int)(unsigned short)s) << 16);
}
__device__ __forceinline__ bf16x8 pack8(float4 a, float4 b) {
    bf16x8 r;
    r[0] = (short)f2bf(a.x); r[1] = (short)f2bf(a.y);
    r[2] = (short)f2bf(a.z); r[3] = (short)f2bf(a.w);
    r[4] = (short)f2bf(b.x); r[5] = (short)f2bf(b.y);
    r[6] = (short)f2bf(b.z); r[7] = (short)f2bf(b.w);
    return r;
}

#define SH_STRIDE 136   // bf16 elems/row (sH): 272B/row = +4 banks/row (measured clean)
#define SW_STRIDE 56    // bf16 elems/row (sW): 112B/row = -4 banks/row (same clean family;
                        // stride 40 (+20 banks) measured 5.1M conflicts in r8)

// barrier that does NOT drain vmcnt: global gather loads stay in flight.
// LDS correctness: lgkmcnt(0) drains all ds_writes (their vmem sources are
// auto-waited by the compiler's data-dependency vmcnt before each ds_write).
__device__ __forceinline__ void bar_lgkm() {
    asm volatile("s_waitcnt lgkmcnt(0)\n\ts_barrier" ::: "memory");
}

// MFMA sweep: B fragments from LDS chunk, 2 row-tiles x 8 col-tiles
__device__ __forceinline__ void mfma_sweep_lds(f32x4 (&acc)[2][8], bf16x8 a0, bf16x8 a1,
                                               const short* sWb, int lm, int lq)
{
#pragma unroll
    for (int ct = 0; ct < 8; ++ct) {
        bf16x8 b = *(const bf16x8*)(sWb + (ct * 16 + lm) * SW_STRIDE + lq * 8);
        acc[0][ct] = __builtin_amdgcn_mfma_f32_16x16x32_bf16(a0, b, acc[0][ct], 0, 0, 0);
        acc[1][ct] = __builtin_amdgcn_mfma_f32_16x16x32_bf16(a1, b, acc[1][ct], 0, 0, 0);
    }
}

// cooperative stage of one 128x32 weight chunk into sW
__device__ __forceinline__ void stage_w(short* __restrict__ sW, const short* __restrict__ Wt,
                                        int Kpad, int k0, int tid)
{
    int r = tid >> 1, h = tid & 1;
    const short* src = Wt + (size_t)r * Kpad + k0 + h * 16;
    short* dst = sW + r * SW_STRIDE + h * 16;
    *(bf16x8*)dst       = *(const bf16x8*)src;
    *(bf16x8*)(dst + 8) = *(const bf16x8*)(src + 8);
}

__device__ __forceinline__ void zero_acc(f32x4 (&acc)[2][8]) {
#pragma unroll
    for (int i = 0; i < 2; ++i)
#pragma unroll
        for (int j = 0; j < 8; ++j) acc[i][j] = (f32x4)(0.f);
}

__device__ __forceinline__ void park(const f32x4 (&acc)[2][8], const float* __restrict__ bias,
                                     short* __restrict__ sH, int w32, int lm, int lq)
{
#pragma unroll
    for (int ct = 0; ct < 8; ++ct) {
        float bb = bias[ct * 16 + lm];
#pragma unroll
        for (int rt = 0; rt < 2; ++rt) {
            int rbase = w32 + rt * 16 + lq * 4;
#pragma unroll
            for (int reg = 0; reg < 4; ++reg) {
                float v = fmaxf(acc[rt][ct][reg] + bb, 0.f);
                sH[(rbase + reg) * SH_STRIDE + ct * 16 + lm] = (short)f2bf(v);
            }
        }
    }
}

// pipelined layer-0 fragment: either bf16 pair or 4 raw float4s (packed at consume
// so the vmcnt wait lands after the staging barriers, not at load time)
struct Frag {
    bf16x8 a0, a1;
    float4 f0, f1, f2, f3;
    int isF;
};

__device__ __forceinline__ void load_frag(Frag& fr, int c, int mode,
    const short* __restrict__ nfb, const float* __restrict__ eff,
    const float* __restrict__ aggf,
    int iS0, int iS1, int iR0, int iR1, size_t eO0, size_t eO1,
    int r0m, int r1m, const short* sH, int w32, int lm, int lq)
{
    int kq = lq * 8;
    fr.isF = 0;
    if (mode == 0) {
        fr.a0 = *(const bf16x8*)&sH[(w32 + lm) * SH_STRIDE + c * 32 + kq];
        fr.a1 = *(const bf16x8*)&sH[(w32 + 16 + lm) * SH_STRIDE + c * 32 + kq];
    } else if (mode == 1) {
        int seg = c >> 2, kb = (c & 3) * 32 + kq;
        if (seg == 0) {
            fr.a0 = *(const bf16x8*)(nfb + (size_t)iS0 * 128 + kb);
            fr.a1 = *(const bf16x8*)(nfb + (size_t)iS1 * 128 + kb);
        } else if (seg == 1) {
            fr.a0 = *(const bf16x8*)(nfb + (size_t)iR0 * 128 + kb);
            fr.a1 = *(const bf16x8*)(nfb + (size_t)iR1 * 128 + kb);
        } else {
            const float* p0 = eff + eO0 + kb;
            const float* p1 = eff + eO1 + kb;
            fr.f0 = *(const float4*)p0; fr.f1 = *(const float4*)(p0 + 4);
            fr.f2 = *(const float4*)p1; fr.f3 = *(const float4*)(p1 + 4);
            fr.isF = 1;
        }
    } else if (mode == 2) {
        int seg = c >> 2, kb = (c & 3) * 32 + kq;
        if (seg == 0) {
            fr.a0 = *(const bf16x8*)(nfb + (size_t)r0m * 128 + kb);
            fr.a1 = *(const bf16x8*)(nfb + (size_t)r1m * 128 + kb);
        } else {
            const float* p0 = aggf + (size_t)r0m * 128 + kb;
            const float* p1 = aggf + (size_t)r1m * 128 + kb;
            fr.f0 = *(const float4*)p0; fr.f1 = *(const float4*)(p0 + 4);
            fr.f2 = *(const float4*)p1; fr.f3 = *(const float4*)(p1 + 4);
            fr.isF = 1;
        }
    } else {
        int kb = c * 32 + kq;
        fr.a0 = *(const bf16x8*)(nfb + (size_t)r0m * 128 + kb);
        fr.a1 = *(const bf16x8*)(nfb + (size_t)r1m * 128 + kb);
    }
}

// modes: 0 = encoder (stage fp32 A0f K0<=32); 1 = edge gather (nfb,nfb,ef) sorted by eList;
//        2 = node concat (nfb, agg fp32); 3 = decoder (nfb; tail 128->3)
__global__ __launch_bounds__(256) void gnn_mlp(
    const short* __restrict__ Wt0, int Kpad0,
    const short* __restrict__ Wt1, const short* __restrict__ Wt2,
    const float* __restrict__ b0, const float* __restrict__ b1, const float* __restrict__ b2,
    const float* __restrict__ g, const float* __restrict__ be,
    const float* __restrict__ A0f, int K0,          // mode0: src; mode3: dec_W2 [128x3]
    const short* __restrict__ nfb,
    const float* __restrict__ eff,
    const float* __restrict__ aggf,
    const int* __restrict__ eList,
    const int* __restrict__ senders, const int* __restrict__ receivers,
    float* __restrict__ outF, short* __restrict__ outB,
    float* __restrict__ aggOut,
    float* __restrict__ decOut,
    int M, int mode, int resid)
{
    __shared__ short sH[128 * SH_STRIDE];
    __shared__ short sW[128 * SW_STRIDE];
    __shared__ int sEdge[128], sRcv[128], sSnd[128];
    const int tid = threadIdx.x;
    const int lane = tid & 63;
    const int w = tid >> 6;           // wave 0..3
    const int lm = lane & 15;
    const int lq = lane >> 4;
    const int w32 = w * 32;
    const int m0 = blockIdx.x * 128;

    if (mode == 1) {
        if (tid < 128) {
            int slot = m0 + tid;                       // grid exact: slot < E
            int e = eList ? eList[slot] : slot;
            sEdge[tid] = e;
            sRcv[tid] = receivers[e];
            sSnd[tid] = senders[e];
        }
        bar_lgkm();
    }

    f32x4 acc[2][8];
    zero_acc(acc);

    // -------- layer 0 (pipelined, lgkm-only barriers) --------
    if (mode == 0) {
        // stage 32 rows x 32 k per wave (zero-padded) into sH as bf16 (wave-private)
#pragma unroll
        for (int i = 0; i < 16; ++i) {
            int flat = lane + i * 64;
            int r = flat >> 5, k = flat & 31;
            int row = m0 + w32 + r;
            float v = (k < K0 && row < M) ? A0f[(size_t)row * K0 + k] : 0.f;
            sH[(w32 + r) * SH_STRIDE + k] = (short)f2bf(v);
        }
    }
    int iS0 = 0, iS1 = 0, iR0 = 0, iR1 = 0;
    size_t eO0 = 0, eO1 = 0;
    if (mode == 1) {
        iS0 = sSnd[w32 + lm]; iS1 = sSnd[w32 + 16 + lm];
        iR0 = sRcv[w32 + lm]; iR1 = sRcv[w32 + 16 + lm];
        eO0 = (size_t)sEdge[w32 + lm] * 128;
        eO1 = (size_t)sEdge[w32 + 16 + lm] * 128;
    }
    const int r0m = min(m0 + w32 + lm, M - 1);
    const int r1m = min(m0 + w32 + 16 + lm, M - 1);
    const int nC0 = Kpad0 >> 5;

    {
        Frag cur, nxt;
        load_frag(cur, 0, mode, nfb, eff, aggf, iS0, iS1, iR0, iR1, eO0, eO1,
                  r0m, r1m, sH, w32, lm, lq);
        for (int c = 0; c < nC0; ++c) {
            if (c + 1 < nC0)
                load_frag(nxt, c + 1, mode, nfb, eff, aggf, iS0, iS1, iR0, iR1, eO0, eO1,
                          r0m, r1m, sH, w32, lm, lq);
            bar_lgkm();                       // all waves done reading previous sW chunk
            stage_w(sW, Wt0, Kpad0, c * 32, tid);
            bar_lgkm();                       // chunk staged (gathers still in flight)
            bf16x8 u0, u1;
            if (cur.isF) { u0 = pack8(cur.f0, cur.f1); u1 = pack8(cur.f2, cur.f3); }
            else         { u0 = cur.a0;               u1 = cur.a1; }
            mfma_sweep_lds(acc, u0, u1, sW, lm, lq);
            cur = nxt;
        }
    }
    bar_lgkm();                               // all waves done with last sW0 chunk
    park(acc, b0, sH, w32, lm, lq);           // h1 (relu) -> LDS, wave-private rows

    // -------- layer 1 --------
    zero_acc(acc);
    for (int c = 0; c < 4; ++c) {
        bf16x8 a0 = *(const bf16x8*)&sH[(w32 + lm) * SH_STRIDE + c * 32 + lq * 8];
        bf16x8 a1 = *(const bf16x8*)&sH[(w32 + 16 + lm) * SH_STRIDE + c * 32 + lq * 8];
        bar_lgkm();
        stage_w(sW, Wt1, 128, c * 32, tid);
        bar_lgkm();
        mfma_sweep_lds(acc, a0, a1, sW, lm, lq);
    }
    bar_lgkm();
    park(acc, b1, sH, w32, lm, lq);

    // -------- decoder tail: h2 @ dec_W2[128x3] + b2 --------
    if (mode == 3) {
#pragma unroll
        for (int t = 0; t < 2; ++t) {
            int idx = t * 64 + lane;
            if (idx < 96) {
                int r = idx / 3, o = idx - r * 3;
                int row = m0 + w32 + r;
                if (row < M) {
                    float s = b2[o];
#pragma unroll
                    for (int kk = 0; kk < 16; ++kk) {
                        bf16x8 h8 = *(const bf16x8*)&sH[(w32 + r) * SH_STRIDE + kk * 8];
#pragma unroll
                        for (int j = 0; j < 8; ++j)
                            s += bf2f(h8[j]) * A0f[(kk * 8 + j) * 3 + o];
                    }
                    decOut[(size_t)row * 3 + o] = s;
                }
            }
        }
        return;
    }

    // -------- layer 2 --------
    zero_acc(acc);
    for (int c = 0; c < 4; ++c) {
        bf16x8 a0 = *(const bf16x8*)&sH[(w32 + lm) * SH_STRIDE + c * 32 + lq * 8];
        bf16x8 a1 = *(const bf16x8*)&sH[(w32 + 16 + lm) * SH_STRIDE + c * 32 + lq * 8];
        bar_lgkm();
        stage_w(sW, Wt2, 128, c * 32, tid);
        bar_lgkm();
        mfma_sweep_lds(acc, a0, a1, sW, lm, lq);
    }

    // -------- epilogue: bias + LN (+ residual / shadow / merged scatter) --------
    float g_[8], be_[8], b2_[8];
#pragma unroll
    for (int ct = 0; ct < 8; ++ct) {
        g_[ct] = g[ct * 16 + lm]; be_[ct] = be[ct * 16 + lm]; b2_[ct] = b2[ct * 16 + lm];
    }

    if (mode == 1) {
#pragma unroll
        for (int rt = 0; rt < 2; ++rt) {
            float run[8];
            int curRcv = -1;
#pragma unroll
            for (int reg = 0; reg < 4; ++reg) {
                int rloc = w32 + rt * 16 + lq * 4 + reg;
                float v[8];
                float s = 0.f;
#pragma unroll
                for (int ct = 0; ct < 8; ++ct) { v[ct] = acc[rt][ct][reg] + b2_[ct]; s += v[ct]; }
                s += __shfl_xor(s, 1); s += __shfl_xor(s, 2);
                s += __shfl_xor(s, 4); s += __shfl_xor(s, 8);
                float mu = s * (1.f / 128.f);
                float q = 0.f;
#pragma unroll
                for (int ct = 0; ct < 8; ++ct) { v[ct] -= mu; q += v[ct] * v[ct]; }
                q += __shfl_xor(q, 1); q += __shfl_xor(q, 2);
                q += __shfl_xor(q, 4); q += __shfl_xor(q, 8);
                float rs = rsqrtf(q * (1.f / 128.f) + 1e-5f);
                int e = sEdge[rloc];
                int rcv = sRcv[rloc];
                float o[8];
#pragma unroll
                for (int ct = 0; ct < 8; ++ct) {
                    o[ct] = v[ct] * rs * g_[ct] + be_[ct];
                    size_t gi = (size_t)e * 128 + ct * 16 + lm;
                    outF[gi] += o[ct];
                }
                if (rcv != curRcv) {
                    if (curRcv >= 0) {
#pragma unroll
                        for (int ct = 0; ct < 8; ++ct)
                            atomicAdd(aggOut + (size_t)curRcv * 128 + ct * 16 + lm, run[ct]);
                    }
                    curRcv = rcv;
#pragma unroll
                    for (int ct = 0; ct < 8; ++ct) run[ct] = o[ct];
                } else {
#pragma unroll
                    for (int ct = 0; ct < 8; ++ct) run[ct] += o[ct];
                }
            }
            if (curRcv >= 0) {
#pragma unroll
                for (int ct = 0; ct < 8; ++ct)
                    atomicAdd(aggOut + (size_t)curRcv * 128 + ct * 16 + lm, run[ct]);
            }
        }
    } else {
#pragma unroll
        for (int rt = 0; rt < 2; ++rt) {
#pragma unroll
            for (int reg = 0; reg < 4; ++reg) {
                int row = m0 + w32 + rt * 16 + lq * 4 + reg;
                float v[8];
                float s = 0.f;
#pragma unroll
                for (int ct = 0; ct < 8; ++ct) { v[ct] = acc[rt][ct][reg] + b2_[ct]; s += v[ct]; }
                s += __shfl_xor(s, 1); s += __shfl_xor(s, 2);
                s += __shfl_xor(s, 4); s += __shfl_xor(s, 8);
                float mu = s * (1.f / 128.f);
                float q = 0.f;
#pragma unroll
                for (int ct = 0; ct < 8; ++ct) { v[ct] -= mu; q += v[ct] * v[ct]; }
                q += __shfl_xor(q, 1); q += __shfl_xor(q, 2);
                q += __shfl_xor(q, 4); q += __shfl_xor(q, 8);
                float rs = rsqrtf(q * (1.f / 128.f) + 1e-5f);
                if (row < M) {
#pragma unroll
                    for (int ct = 0; ct < 8; ++ct) {
                        float o = v[ct] * rs * g_[ct] + be_[ct];
                        size_t gi = (size_t)row * 128 + ct * 16 + lm;
                        if (resid) {
                            float ns = outF[gi] + o;
                            outF[gi] = ns;
                            if (outB) outB[gi] = (short)f2bf(ns);
                        } else {
                            outF[gi] = o;
                            if (outB) outB[gi] = (short)f2bf(o);
                        }
                    }
                }
            }
        }
    }
}

// ---------------------------------------------------------------------------
// counting-sort of edges by receiver: cnt -> exclusive-prefix cursor -> fill
// ---------------------------------------------------------------------------
__global__ void zero_i(int* __restrict__ p, int n)
{
    int i = blockIdx.x * 256 + threadIdx.x;
    if (i < n) p[i] = 0;
}
__global__ void csr_count(const int* __restrict__ recv, int* __restrict__ cnt, int E)
{
    int i = blockIdx.x * 256 + threadIdx.x;
    if (i < E) atomicAdd(&cnt[recv[i]], 1);
}
__global__ __launch_bounds__(256) void csr_scan(const int* __restrict__ cnt,
                                                int* __restrict__ cursor, int N)
{
    __shared__ int ssum[257];
    const int tid = threadIdx.x;
    const int per = (N + 255) / 256;
    const int lo = tid * per, hi = min(lo + per, N);
    int s = 0;
    for (int i = lo; i < hi; ++i) s += cnt[i];
    ssum[tid] = s;
    __syncthreads();
    if (tid == 0) {
        int run = 0;
        for (int i = 0; i < 256; ++i) { int t = ssum[i]; ssum[i] = run; run += t; }
        ssum[256] = run;
    }
    __syncthreads();
    int run = ssum[tid];
    for (int i = lo; i < hi; ++i) { int c = cnt[i]; cursor[i] = run; run += c; }
}
__global__ void csr_fill(const int* __restrict__ recv, int* __restrict__ cursor,
                         int* __restrict__ eList, int E)
{
    int i = blockIdx.x * 256 + threadIdx.x;
    if (i < E) {
        int pos = atomicAdd(&cursor[recv[i]], 1);
        eList[pos] = i;
    }
}

// ---------------------------------------------------------------------------
struct WtPrep { const float* src; int K; int Kpad; int dstOff; };
struct WtPrepAll { WtPrep m[26]; };

__global__ void wt_prep_kernel(WtPrepAll all, short* __restrict__ dst)
{
    const WtPrep p = all.m[blockIdx.y];
    int total = 128 * p.Kpad;
    int idx = blockIdx.x * 256 + threadIdx.x;
    if (idx >= total) return;
    int n = idx / p.Kpad, k = idx - n * p.Kpad;
    float v = (k < p.K) ? p.src[(size_t)k * 128 + n] : 0.f;
    dst[p.dstOff + idx] = (short)f2bf(v);
}

__global__ void zero_kernel(float4* __restrict__ p, long n4)
{
    long i = (long)blockIdx.x * blockDim.x + threadIdx.x;
    if (i < n4) p[i] = make_float4(0.f, 0.f, 0.f, 0.f);
}

// ---------------------------------------------------------------------------
extern "C" void kernel_launch(void* const* d_in, const int* in_sizes, int n_in,
                              void* d_out, int out_size, void* d_ws, size_t ws_size,
                              hipStream_t stream)
{
    const float* node_x   = (const float*)d_in[0];
    const float* edge_x   = (const float*)d_in[1];
    const float* enc_n_W0 = (const float*)d_in[2];
    const float* enc_n_b0 = (const float*)d_in[3];
    const float* enc_n_W1 = (const float*)d_in[4];
    const float* enc_n_b1 = (const float*)d_in[5];
    const float* enc_n_W2 = (const float*)d_in[6];
    const float* enc_n_b2 = (const float*)d_in[7];
    const float* enc_n_g  = (const float*)d_in[8];
    const float* enc_n_be = (const float*)d_in[9];
    const float* enc_e_W0 = (const float*)d_in[10];
    const float* enc_e_b0 = (const float*)d_in[11];
    const float* enc_e_W1 = (const float*)d_in[12];
    const float* enc_e_b1 = (const float*)d_in[13];
    const float* enc_e_W2 = (const float*)d_in[14];
    const float* enc_e_b2 = (const float*)d_in[15];
    const float* enc_e_g  = (const float*)d_in[16];
    const float* enc_e_be = (const float*)d_in[17];
    const float* gnb_e_W0 = (const float*)d_in[18];
    const float* gnb_e_b0 = (const float*)d_in[19];
    const float* gnb_e_W1 = (const float*)d_in[20];
    const float* gnb_e_b1 = (const float*)d_in[21];
    const float* gnb_e_W2 = (const float*)d_in[22];
    const float* gnb_e_b2 = (const float*)d_in[23];
    const float* gnb_e_g  = (const float*)d_in[24];
    const float* gnb_e_be = (const float*)d_in[25];
    const float* gnb_n_W0 = (const float*)d_in[26];
    const float* gnb_n_b0 = (const float*)d_in[27];
    const float* gnb_n_W1 = (const float*)d_in[28];
    const float* gnb_n_b1 = (const float*)d_in[29];
    const float* gnb_n_W2 = (const float*)d_in[30];
    const float* gnb_n_b2 = (const float*)d_in[31];
    const float* gnb_n_g  = (const float*)d_in[32];
    const float* gnb_n_be = (const float*)d_in[33];
    const float* dec_W0   = (const float*)d_in[34];
    const float* dec_b0   = (const float*)d_in[35];
    const float* dec_W1   = (const float*)d_in[36];
    const float* dec_b1   = (const float*)d_in[37];
    const float* dec_W2   = (const float*)d_in[38];
    const float* dec_b2   = (const float*)d_in[39];
    const int*   senders  = (const int*)d_in[40];
    const int*   receivers= (const int*)d_in[41];
    float* out = (float*)d_out;

    const int N = NN, E = EE;
    const int WT_TOTAL = (32 + 128 + 128 + 32 + 128 + 128 + 3 * (384 + 128 + 128 + 256 + 128 + 128)
                          + 128 + 128) * 128;

    // ---- workspace layout: identical to round 6/8 (109.26 MB, known-good) ----
    float* nf   = (float*)d_ws;
    float* agg  = nf + (size_t)N * 128;
    float* ef   = agg + (size_t)N * 128;
    short* nfbf = (short*)(ef + (size_t)E * 128);
    short* wt   = nfbf + (size_t)N * 128;
    int*   eList = (int*)(wt + WT_TOTAL);
    size_t need_sorted = (size_t)((char*)(eList + E) - (char*)d_ws);
    int* cnt    = (int*)agg;
    int* cursor = cnt + N;

    const bool useSorted = (ws_size >= need_sorted);
    const int* eL = useSorted ? eList : nullptr;

    WtPrepAll tbl;
    int nMat = 0, off = 0;
    int o_encn[3], o_ence[3], o_ge0[3], o_ge1[3], o_ge2[3], o_gn0[3], o_gn1[3], o_gn2[3], o_dec[2];
    auto add = [&](const float* src, int K, int Kpad) {
        tbl.m[nMat].src = src; tbl.m[nMat].K = K; tbl.m[nMat].Kpad = Kpad;
        tbl.m[nMat].dstOff = off;
        int r = off; off += 128 * Kpad; ++nMat; return r;
    };
    o_encn[0] = add(enc_n_W0, 12, 32);
    o_encn[1] = add(enc_n_W1, 128, 128);
    o_encn[2] = add(enc_n_W2, 128, 128);
    o_ence[0] = add(enc_e_W0, 7, 32);
    o_ence[1] = add(enc_e_W1, 128, 128);
    o_ence[2] = add(enc_e_W2, 128, 128);
    for (int s = 0; s < 3; ++s) {
        o_ge0[s] = add(gnb_e_W0 + (size_t)s * 384 * 128, 384, 384);
        o_ge1[s] = add(gnb_e_W1 + (size_t)s * 128 * 128, 128, 128);
        o_ge2[s] = add(gnb_e_W2 + (size_t)s * 128 * 128, 128, 128);
        o_gn0[s] = add(gnb_n_W0 + (size_t)s * 256 * 128, 256, 256);
        o_gn1[s] = add(gnb_n_W1 + (size_t)s * 128 * 128, 128, 128);
        o_gn2[s] = add(gnb_n_W2 + (size_t)s * 128 * 128, 128, 128);
    }
    o_dec[0] = add(dec_W0, 128, 128);
    o_dec[1] = add(dec_W1, 128, 128);

    wt_prep_kernel<<<dim3(192, 26), 256, 0, stream>>>(tbl, wt);

    if (useSorted) {
        zero_i<<<dim3((N + 255) / 256), 256, 0, stream>>>(cnt, N);
        csr_count<<<dim3((E + 255) / 256), 256, 0, stream>>>(receivers, cnt, E);
        csr_scan<<<dim3(1), 256, 0, stream>>>(cnt, cursor, N);
        csr_fill<<<dim3((E + 255) / 256), 256, 0, stream>>>(receivers, cursor, eList, E);
    }

    const dim3 gN((N + 127) / 128), gE(E / 128);

    // ---- encoders ----
    gnn_mlp<<<gN, 256, 0, stream>>>(wt + o_encn[0], 32, wt + o_encn[1], wt + o_encn[2],
        enc_n_b0, enc_n_b1, enc_n_b2, enc_n_g, enc_n_be,
        node_x, 12, nullptr, nullptr, nullptr, nullptr, nullptr, nullptr,
        nf, nfbf, nullptr, nullptr, N, 0, 0);
    gnn_mlp<<<gE, 256, 0, stream>>>(wt + o_ence[0], 32, wt + o_ence[1], wt + o_ence[2],
        enc_e_b0, enc_e_b1, enc_e_b2, enc_e_g, enc_e_be,
        edge_x, 7, nullptr, nullptr, nullptr, nullptr, nullptr, nullptr,
        ef, nullptr, nullptr, nullptr, E, 0, 0);

    // ---- 3 message-passing steps ----
    for (int s = 0; s < 3; ++s) {
        const float* eb0 = gnb_e_b0 + (size_t)s * 128;
        const float* eb1 = gnb_e_b1 + (size_t)s * 128;
        const float* eb2 = gnb_e_b2 + (size_t)s * 128;
        const float* eg  = gnb_e_g  + (size_t)s * 128;
        const float* ebe = gnb_e_be + (size_t)s * 128;
        const float* nb0 = gnb_n_b0 + (size_t)s * 128;
        const float* nb1 = gnb_n_b1 + (size_t)s * 128;
        const float* nb2 = gnb_n_b2 + (size_t)s * 128;
        const float* ng  = gnb_n_g  + (size_t)s * 128;
        const float* nbe = gnb_n_be + (size_t)s * 128;

        zero_kernel<<<dim3((N * 32 + 255) / 256), 256, 0, stream>>>((float4*)agg, (long)N * 32);
        gnn_mlp<<<gE, 256, 0, stream>>>(wt + o_ge0[s], 384, wt + o_ge1[s], wt + o_ge2[s],
            eb0, eb1, eb2, eg, ebe,
            nullptr, 0, nfbf, ef, nullptr, eL, senders, receivers,
            ef, nullptr, agg, nullptr, E, 1, 1);
        gnn_mlp<<<gN, 256, 0, stream>>>(wt + o_gn0[s], 256, wt + o_gn1[s], wt + o_gn2[s],
            nb0, nb1, nb2, ng, nbe,
            nullptr, 0, nfbf, nullptr, agg, nullptr, nullptr, nullptr,
            nf, nfbf, nullptr, nullptr, N, 2, 1);
    }

    // ---- decoder ----
    gnn_mlp<<<gN, 256, 0, stream>>>(wt + o_dec[0], 128, wt + o_dec[1], nullptr,
        dec_b0, dec_b1, dec_b2, nullptr, nullptr,
        dec_W2, 0, nfbf, nullptr, nullptr, nullptr, nullptr, nullptr,
        nullptr, nullptr, nullptr, out, N, 3, 0);
}

// Round 11
// 727.311 us; speedup vs baseline: 1.2007x; 1.0491x over previous
//
#include <hip/hip_runtime.h>
#include <hip/hip_bf16.h>

#define NN 20000
#define EE 160000

typedef __attribute__((ext_vector_type(8))) short bf16x8;
typedef __attribute__((ext_vector_type(4))) float f32x4;

__device__ __forceinline__ unsigned short f2bf(float f) {
    unsigned int u = __float_as_uint(f);
    u += 0x7FFFu + ((u >> 16) & 1);   // RNE
    return (unsigned short)(u >> 16);
}
__device__ __forceinline__ float bf2f(short s) {
    return __uint_as_float(((unsigned int)(unsigned short)s) << 16);
}
__device__ __forceinline__ bf16x8 pack8(float4 a, float4 b) {
    bf16x8 r;
    r[0] = (short)f2bf(a.x); r[1] = (short)f2bf(a.y);
    r[2] = (short)f2bf(a.z); r[3] = (short)f2bf(a.w);
    r[4] = (short)f2bf(b.x); r[5] = (short)f2bf(b.y);
    r[6] = (short)f2bf(b.z); r[7] = (short)f2bf(b.w);
    return r;
}

#define SH_STRIDE 136
#define SW_STRIDE 56

// barrier that does NOT drain vmcnt (gathers stay in flight)
__device__ __forceinline__ void bar_lgkm() {
    asm volatile("s_waitcnt lgkmcnt(0)\n\ts_barrier" ::: "memory");
}

__device__ __forceinline__ void mfma_sweep_lds(f32x4 (&acc)[2][8], bf16x8 a0, bf16x8 a1,
                                               const short* sWb, int lm, int lq)
{
#pragma unroll
    for (int ct = 0; ct < 8; ++ct) {
        bf16x8 b = *(const bf16x8*)(sWb + (ct * 16 + lm) * SW_STRIDE + lq * 8);
        acc[0][ct] = __builtin_amdgcn_mfma_f32_16x16x32_bf16(a0, b, acc[0][ct], 0, 0, 0);
        acc[1][ct] = __builtin_amdgcn_mfma_f32_16x16x32_bf16(a1, b, acc[1][ct], 0, 0, 0);
    }
}

template<int NT>
__device__ __forceinline__ void stage_w(short* __restrict__ sW, const short* __restrict__ Wt,
                                        int Kpad, int k0, int tid)
{
    for (int i = tid; i < 256; i += NT) {
        int r = i >> 1, h = i & 1;
        const short* src = Wt + (size_t)r * Kpad + k0 + h * 16;
        short* dst = sW + r * SW_STRIDE + h * 16;
        *(bf16x8*)dst       = *(const bf16x8*)src;
        *(bf16x8*)(dst + 8) = *(const bf16x8*)(src + 8);
    }
}

__device__ __forceinline__ void zero_acc(f32x4 (&acc)[2][8]) {
#pragma unroll
    for (int i = 0; i < 2; ++i)
#pragma unroll
        for (int j = 0; j < 8; ++j) acc[i][j] = (f32x4)(0.f);
}

__device__ __forceinline__ void park(const f32x4 (&acc)[2][8], const float* __restrict__ bias,
                                     short* __restrict__ sH, int w32, int lm, int lq)
{
#pragma unroll
    for (int ct = 0; ct < 8; ++ct) {
        float bb = bias[ct * 16 + lm];
#pragma unroll
        for (int rt = 0; rt < 2; ++rt) {
            int rbase = w32 + rt * 16 + lq * 4;
#pragma unroll
            for (int reg = 0; reg < 4; ++reg) {
                float v = fmaxf(acc[rt][ct][reg] + bb, 0.f);
                sH[(rbase + reg) * SH_STRIDE + ct * 16 + lm] = (short)f2bf(v);
            }
        }
    }
}

struct Frag {
    bf16x8 a0, a1;
    float4 f0, f1, f2, f3;
    int isF;
};

__device__ __forceinline__ void load_frag(Frag& fr, int c, int mode,
    const short* __restrict__ nfb, const float* __restrict__ eff,
    const float* __restrict__ aggf,
    int iS0, int iS1, int iR0, int iR1, size_t eO0, size_t eO1,
    int r0m, int r1m, const short* sH, int w32, int lm, int lq)
{
    int kq = lq * 8;
    fr.isF = 0;
    if (mode == 0) {
        fr.a0 = *(const bf16x8*)&sH[(w32 + lm) * SH_STRIDE + c * 32 + kq];
        fr.a1 = *(const bf16x8*)&sH[(w32 + 16 + lm) * SH_STRIDE + c * 32 + kq];
    } else if (mode == 1) {
        int seg = c >> 2, kb = (c & 3) * 32 + kq;
        if (seg == 0) {
            fr.a0 = *(const bf16x8*)(nfb + (size_t)iS0 * 128 + kb);
            fr.a1 = *(const bf16x8*)(nfb + (size_t)iS1 * 128 + kb);
        } else if (seg == 1) {
            fr.a0 = *(const bf16x8*)(nfb + (size_t)iR0 * 128 + kb);
            fr.a1 = *(const bf16x8*)(nfb + (size_t)iR1 * 128 + kb);
        } else {
            const float* p0 = eff + eO0 + kb;
            const float* p1 = eff + eO1 + kb;
            fr.f0 = *(const float4*)p0; fr.f1 = *(const float4*)(p0 + 4);
            fr.f2 = *(const float4*)p1; fr.f3 = *(const float4*)(p1 + 4);
            fr.isF = 1;
        }
    } else if (mode == 2) {
        int seg = c >> 2, kb = (c & 3) * 32 + kq;
        if (seg == 0) {
            fr.a0 = *(const bf16x8*)(nfb + (size_t)r0m * 128 + kb);
            fr.a1 = *(const bf16x8*)(nfb + (size_t)r1m * 128 + kb);
        } else {
            const float* p0 = aggf + (size_t)r0m * 128 + kb;
            const float* p1 = aggf + (size_t)r1m * 128 + kb;
            fr.f0 = *(const float4*)p0; fr.f1 = *(const float4*)(p0 + 4);
            fr.f2 = *(const float4*)p1; fr.f3 = *(const float4*)(p1 + 4);
            fr.isF = 1;
        }
    } else {
        int kb = c * 32 + kq;
        fr.a0 = *(const bf16x8*)(nfb + (size_t)r0m * 128 + kb);
        fr.a1 = *(const bf16x8*)(nfb + (size_t)r1m * 128 + kb);
    }
}

// NW waves per block, 32 rows per wave.
// modes: 0 encoder; 1 edge (sorted, rt-interleaved slots); 2 node; 3 decoder
template<int NW>
__global__ __launch_bounds__(NW * 64) void gnn_mlp(
    const short* __restrict__ Wt0, int Kpad0,
    const short* __restrict__ Wt1, const short* __restrict__ Wt2,
    const float* __restrict__ b0, const float* __restrict__ b1, const float* __restrict__ b2,
    const float* __restrict__ g, const float* __restrict__ be,
    const float* __restrict__ A0f, int K0,
    const short* __restrict__ nfb,
    const float* __restrict__ eff,
    const float* __restrict__ aggf,
    const int* __restrict__ eList,
    const int* __restrict__ senders, const int* __restrict__ receivers,
    float* __restrict__ outF, short* __restrict__ outB,
    float* __restrict__ aggOut,
    float* __restrict__ decOut,
    int M, int mode, int resid)
{
    __shared__ short sH[NW * 32 * SH_STRIDE];
    __shared__ short sW[128 * SW_STRIDE];
    __shared__ int sEdge[NW * 32], sRcv[NW * 32], sSnd[NW * 32];
    const int tid = threadIdx.x;
    const int lane = tid & 63;
    const int w = tid >> 6;
    const int lm = lane & 15;
    const int lq = lane >> 4;
    const int w32 = w * 32;
    const int m0 = blockIdx.x * (NW * 32);

    if (mode == 1) {
        if (tid < NW * 32) {
            int slot = m0 + tid;                       // grid exact: slot < E
            int e = eList ? eList[slot] : slot;
            sEdge[tid] = e;
            sRcv[tid] = receivers[e];
            sSnd[tid] = senders[e];
        }
        bar_lgkm();
    }

    f32x4 acc[2][8];
    zero_acc(acc);

    // -------- layer 0 (pipelined, lgkm-only barriers) --------
    if (mode == 0) {
#pragma unroll
        for (int i = 0; i < 16; ++i) {
            int flat = lane + i * 64;
            int r = flat >> 5, k = flat & 31;
            int row = m0 + w32 + r;
            float v = (k < K0 && row < M) ? A0f[(size_t)row * K0 + k] : 0.f;
            sH[(w32 + r) * SH_STRIDE + k] = (short)f2bf(v);
        }
    }
    int iS0 = 0, iS1 = 0, iR0 = 0, iR1 = 0;
    size_t eO0 = 0, eO1 = 0;
    if (mode == 1) {
        // rt-interleaved: MFMA row m of tile rt <-> sorted slot w32 + 2*m + rt.
        // Lane lm gathers slots w32+2*lm (rt0) and w32+2*lm+1 (rt1).
        int s0 = w32 + 2 * lm, s1 = s0 + 1;
        iS0 = sSnd[s0]; iS1 = sSnd[s1];
        iR0 = sRcv[s0]; iR1 = sRcv[s1];
        eO0 = (size_t)sEdge[s0] * 128;
        eO1 = (size_t)sEdge[s1] * 128;
    }
    const int r0m = min(m0 + w32 + lm, M - 1);
    const int r1m = min(m0 + w32 + 16 + lm, M - 1);
    const int nC0 = Kpad0 >> 5;

    {
        Frag cur, nxt;
        load_frag(cur, 0, mode, nfb, eff, aggf, iS0, iS1, iR0, iR1, eO0, eO1,
                  r0m, r1m, sH, w32, lm, lq);
        for (int c = 0; c < nC0; ++c) {
            if (c + 1 < nC0)
                load_frag(nxt, c + 1, mode, nfb, eff, aggf, iS0, iS1, iR0, iR1, eO0, eO1,
                          r0m, r1m, sH, w32, lm, lq);
            bar_lgkm();
            stage_w<NW * 64>(sW, Wt0, Kpad0, c * 32, tid);
            bar_lgkm();
            bf16x8 u0, u1;
            if (cur.isF) { u0 = pack8(cur.f0, cur.f1); u1 = pack8(cur.f2, cur.f3); }
            else         { u0 = cur.a0;               u1 = cur.a1; }
            mfma_sweep_lds(acc, u0, u1, sW, lm, lq);
            cur = nxt;
        }
    }
    bar_lgkm();
    park(acc, b0, sH, w32, lm, lq);

    // -------- layer 1 --------
    zero_acc(acc);
    for (int c = 0; c < 4; ++c) {
        bf16x8 a0 = *(const bf16x8*)&sH[(w32 + lm) * SH_STRIDE + c * 32 + lq * 8];
        bf16x8 a1 = *(const bf16x8*)&sH[(w32 + 16 + lm) * SH_STRIDE + c * 32 + lq * 8];
        bar_lgkm();
        stage_w<NW * 64>(sW, Wt1, 128, c * 32, tid);
        bar_lgkm();
        mfma_sweep_lds(acc, a0, a1, sW, lm, lq);
    }
    bar_lgkm();
    park(acc, b1, sH, w32, lm, lq);

    // -------- decoder tail --------
    if (mode == 3) {
#pragma unroll
        for (int t = 0; t < 2; ++t) {
            int idx = t * 64 + lane;
            if (idx < 96) {
                int r = idx / 3, o = idx - r * 3;
                int row = m0 + w32 + r;
                if (row < M) {
                    float s = b2[o];
#pragma unroll
                    for (int kk = 0; kk < 16; ++kk) {
                        bf16x8 h8 = *(const bf16x8*)&sH[(w32 + r) * SH_STRIDE + kk * 8];
#pragma unroll
                        for (int j = 0; j < 8; ++j)
                            s += bf2f(h8[j]) * A0f[(kk * 8 + j) * 3 + o];
                    }
                    decOut[(size_t)row * 3 + o] = s;
                }
            }
        }
        return;
    }

    // -------- layer 2 --------
    zero_acc(acc);
    for (int c = 0; c < 4; ++c) {
        bf16x8 a0 = *(const bf16x8*)&sH[(w32 + lm) * SH_STRIDE + c * 32 + lq * 8];
        bf16x8 a1 = *(const bf16x8*)&sH[(w32 + 16 + lm) * SH_STRIDE + c * 32 + lq * 8];
        bar_lgkm();
        stage_w<NW * 64>(sW, Wt2, 128, c * 32, tid);
        bar_lgkm();
        mfma_sweep_lds(acc, a0, a1, sW, lm, lq);
    }

    // -------- epilogue --------
    float g_[8], be_[8], b2_[8];
#pragma unroll
    for (int ct = 0; ct < 8; ++ct) {
        g_[ct] = g[ct * 16 + lm]; be_[ct] = be[ct * 16 + lm]; b2_[ct] = b2[ct * 16 + lm];
    }

    if (mode == 1) {
        // lane's 8 C-rows are 8 CONSECUTIVE sorted slots (j = reg*2+rt): one merge run
        float run[8];
        int curRcv = -1;
#pragma unroll
        for (int j = 0; j < 8; ++j) {
            int rt = j & 1, reg = j >> 1;
            int rloc = w32 + lq * 8 + j;               // = w32 + 2*(lq*4+reg) + rt
            float v[8];
            float s = 0.f;
#pragma unroll
            for (int ct = 0; ct < 8; ++ct) { v[ct] = acc[rt][ct][reg] + b2_[ct]; s += v[ct]; }
            s += __shfl_xor(s, 1); s += __shfl_xor(s, 2);
            s += __shfl_xor(s, 4); s += __shfl_xor(s, 8);
            float mu = s * (1.f / 128.f);
            float q = 0.f;
#pragma unroll
            for (int ct = 0; ct < 8; ++ct) { v[ct] -= mu; q += v[ct] * v[ct]; }
            q += __shfl_xor(q, 1); q += __shfl_xor(q, 2);
            q += __shfl_xor(q, 4); q += __shfl_xor(q, 8);
            float rs = rsqrtf(q * (1.f / 128.f) + 1e-5f);
            int e = sEdge[rloc];
            int rcv = sRcv[rloc];
            float o[8];
#pragma unroll
            for (int ct = 0; ct < 8; ++ct) {
                o[ct] = v[ct] * rs * g_[ct] + be_[ct];
                size_t gi = (size_t)e * 128 + ct * 16 + lm;
                outF[gi] += o[ct];                      // ef residual
            }
            if (rcv != curRcv) {
                if (curRcv >= 0) {
#pragma unroll
                    for (int ct = 0; ct < 8; ++ct)
                        atomicAdd(aggOut + (size_t)curRcv * 128 + ct * 16 + lm, run[ct]);
                }
                curRcv = rcv;
#pragma unroll
                for (int ct = 0; ct < 8; ++ct) run[ct] = o[ct];
            } else {
#pragma unroll
                for (int ct = 0; ct < 8; ++ct) run[ct] += o[ct];
            }
        }
        if (curRcv >= 0) {
#pragma unroll
            for (int ct = 0; ct < 8; ++ct)
                atomicAdd(aggOut + (size_t)curRcv * 128 + ct * 16 + lm, run[ct]);
        }
    } else {
#pragma unroll
        for (int rt = 0; rt < 2; ++rt) {
#pragma unroll
            for (int reg = 0; reg < 4; ++reg) {
                int row = m0 + w32 + rt * 16 + lq * 4 + reg;
                float v[8];
                float s = 0.f;
#pragma unroll
                for (int ct = 0; ct < 8; ++ct) { v[ct] = acc[rt][ct][reg] + b2_[ct]; s += v[ct]; }
                s += __shfl_xor(s, 1); s += __shfl_xor(s, 2);
                s += __shfl_xor(s, 4); s += __shfl_xor(s, 8);
                float mu = s * (1.f / 128.f);
                float q = 0.f;
#pragma unroll
                for (int ct = 0; ct < 8; ++ct) { v[ct] -= mu; q += v[ct] * v[ct]; }
                q += __shfl_xor(q, 1); q += __shfl_xor(q, 2);
                q += __shfl_xor(q, 4); q += __shfl_xor(q, 8);
                float rs = rsqrtf(q * (1.f / 128.f) + 1e-5f);
                if (row < M) {
#pragma unroll
                    for (int ct = 0; ct < 8; ++ct) {
                        float o = v[ct] * rs * g_[ct] + be_[ct];
                        size_t gi = (size_t)row * 128 + ct * 16 + lm;
                        if (resid) {
                            float ns = outF[gi] + o;
                            outF[gi] = ns;
                            if (outB) outB[gi] = (short)f2bf(ns);
                        } else {
                            outF[gi] = o;
                            if (outB) outB[gi] = (short)f2bf(o);
                        }
                    }
                }
            }
        }
    }
}

// ---------------------------------------------------------------------------
__global__ void zero_i(int* __restrict__ p, int n)
{
    int i = blockIdx.x * 256 + threadIdx.x;
    if (i < n) p[i] = 0;
}
__global__ void csr_count(const int* __restrict__ recv, int* __restrict__ cnt, int E)
{
    int i = blockIdx.x * 256 + threadIdx.x;
    if (i < E) atomicAdd(&cnt[recv[i]], 1);
}
__global__ __launch_bounds__(256) void csr_scan(const int* __restrict__ cnt,
                                                int* __restrict__ cursor, int N)
{
    __shared__ int ssum[257];
    const int tid = threadIdx.x;
    const int per = (N + 255) / 256;
    const int lo = tid * per, hi = min(lo + per, N);
    int s = 0;
    for (int i = lo; i < hi; ++i) s += cnt[i];
    ssum[tid] = s;
    __syncthreads();
    if (tid == 0) {
        int run = 0;
        for (int i = 0; i < 256; ++i) { int t = ssum[i]; ssum[i] = run; run += t; }
        ssum[256] = run;
    }
    __syncthreads();
    int run = ssum[tid];
    for (int i = lo; i < hi; ++i) { int c = cnt[i]; cursor[i] = run; run += c; }
}
__global__ void csr_fill(const int* __restrict__ recv, int* __restrict__ cursor,
                         int* __restrict__ eList, int E)
{
    int i = blockIdx.x * 256 + threadIdx.x;
    if (i < E) {
        int pos = atomicAdd(&cursor[recv[i]], 1);
        eList[pos] = i;
    }
}

// ---------------------------------------------------------------------------
struct WtPrep { const float* src; int K; int Kpad; int dstOff; };
struct WtPrepAll { WtPrep m[26]; };

__global__ void wt_prep_kernel(WtPrepAll all, short* __restrict__ dst)
{
    const WtPrep p = all.m[blockIdx.y];
    int total = 128 * p.Kpad;
    int idx = blockIdx.x * 256 + threadIdx.x;
    if (idx >= total) return;
    int n = idx / p.Kpad, k = idx - n * p.Kpad;
    float v = (k < p.K) ? p.src[(size_t)k * 128 + n] : 0.f;
    dst[p.dstOff + idx] = (short)f2bf(v);
}

__global__ void zero_kernel(float4* __restrict__ p, long n4)
{
    long i = (long)blockIdx.x * blockDim.x + threadIdx.x;
    if (i < n4) p[i] = make_float4(0.f, 0.f, 0.f, 0.f);
}

// ---------------------------------------------------------------------------
extern "C" void kernel_launch(void* const* d_in, const int* in_sizes, int n_in,
                              void* d_out, int out_size, void* d_ws, size_t ws_size,
                              hipStream_t stream)
{
    const float* node_x   = (const float*)d_in[0];
    const float* edge_x   = (const float*)d_in[1];
    const float* enc_n_W0 = (const float*)d_in[2];
    const float* enc_n_b0 = (const float*)d_in[3];
    const float* enc_n_W1 = (const float*)d_in[4];
    const float* enc_n_b1 = (const float*)d_in[5];
    const float* enc_n_W2 = (const float*)d_in[6];
    const float* enc_n_b2 = (const float*)d_in[7];
    const float* enc_n_g  = (const float*)d_in[8];
    const float* enc_n_be = (const float*)d_in[9];
    const float* enc_e_W0 = (const float*)d_in[10];
    const float* enc_e_b0 = (const float*)d_in[11];
    const float* enc_e_W1 = (const float*)d_in[12];
    const float* enc_e_b1 = (const float*)d_in[13];
    const float* enc_e_W2 = (const float*)d_in[14];
    const float* enc_e_b2 = (const float*)d_in[15];
    const float* enc_e_g  = (const float*)d_in[16];
    const float* enc_e_be = (const float*)d_in[17];
    const float* gnb_e_W0 = (const float*)d_in[18];
    const float* gnb_e_b0 = (const float*)d_in[19];
    const float* gnb_e_W1 = (const float*)d_in[20];
    const float* gnb_e_b1 = (const float*)d_in[21];
    const float* gnb_e_W2 = (const float*)d_in[22];
    const float* gnb_e_b2 = (const float*)d_in[23];
    const float* gnb_e_g  = (const float*)d_in[24];
    const float* gnb_e_be = (const float*)d_in[25];
    const float* gnb_n_W0 = (const float*)d_in[26];
    const float* gnb_n_b0 = (const float*)d_in[27];
    const float* gnb_n_W1 = (const float*)d_in[28];
    const float* gnb_n_b1 = (const float*)d_in[29];
    const float* gnb_n_W2 = (const float*)d_in[30];
    const float* gnb_n_b2 = (const float*)d_in[31];
    const float* gnb_n_g  = (const float*)d_in[32];
    const float* gnb_n_be = (const float*)d_in[33];
    const float* dec_W0   = (const float*)d_in[34];
    const float* dec_b0   = (const float*)d_in[35];
    const float* dec_W1   = (const float*)d_in[36];
    const float* dec_b1   = (const float*)d_in[37];
    const float* dec_W2   = (const float*)d_in[38];
    const float* dec_b2   = (const float*)d_in[39];
    const int*   senders  = (const int*)d_in[40];
    const int*   receivers= (const int*)d_in[41];
    float* out = (float*)d_out;

    const int N = NN, E = EE;
    const int WT_TOTAL = (32 + 128 + 128 + 32 + 128 + 128 + 3 * (384 + 128 + 128 + 256 + 128 + 128)
                          + 128 + 128) * 128;

    // ---- workspace layout: identical to round 6/8/10 (109.26 MB, known-good) ----
    float* nf   = (float*)d_ws;
    float* agg  = nf + (size_t)N * 128;
    float* ef   = agg + (size_t)N * 128;
    short* nfbf = (short*)(ef + (size_t)E * 128);
    short* wt   = nfbf + (size_t)N * 128;
    int*   eList = (int*)(wt + WT_TOTAL);
    size_t need_sorted = (size_t)((char*)(eList + E) - (char*)d_ws);
    int* cnt    = (int*)agg;
    int* cursor = cnt + N;

    const bool useSorted = (ws_size >= need_sorted);
    const int* eL = useSorted ? eList : nullptr;

    WtPrepAll tbl;
    int nMat = 0, off = 0;
    int o_encn[3], o_ence[3], o_ge0[3], o_ge1[3], o_ge2[3], o_gn0[3], o_gn1[3], o_gn2[3], o_dec[2];
    auto add = [&](const float* src, int K, int Kpad) {
        tbl.m[nMat].src = src; tbl.m[nMat].K = K; tbl.m[nMat].Kpad = Kpad;
        tbl.m[nMat].dstOff = off;
        int r = off; off += 128 * Kpad; ++nMat; return r;
    };
    o_encn[0] = add(enc_n_W0, 12, 32);
    o_encn[1] = add(enc_n_W1, 128, 128);
    o_encn[2] = add(enc_n_W2, 128, 128);
    o_ence[0] = add(enc_e_W0, 7, 32);
    o_ence[1] = add(enc_e_W1, 128, 128);
    o_ence[2] = add(enc_e_W2, 128, 128);
    for (int s = 0; s < 3; ++s) {
        o_ge0[s] = add(gnb_e_W0 + (size_t)s * 384 * 128, 384, 384);
        o_ge1[s] = add(gnb_e_W1 + (size_t)s * 128 * 128, 128, 128);
        o_ge2[s] = add(gnb_e_W2 + (size_t)s * 128 * 128, 128, 128);
        o_gn0[s] = add(gnb_n_W0 + (size_t)s * 256 * 128, 256, 256);
        o_gn1[s] = add(gnb_n_W1 + (size_t)s * 128 * 128, 128, 128);
        o_gn2[s] = add(gnb_n_W2 + (size_t)s * 128 * 128, 128, 128);
    }
    o_dec[0] = add(dec_W0, 128, 128);
    o_dec[1] = add(dec_W1, 128, 128);

    wt_prep_kernel<<<dim3(192, 26), 256, 0, stream>>>(tbl, wt);

    if (useSorted) {
        zero_i<<<dim3((N + 255) / 256), 256, 0, stream>>>(cnt, N);
        csr_count<<<dim3((E + 255) / 256), 256, 0, stream>>>(receivers, cnt, E);
        csr_scan<<<dim3(1), 256, 0, stream>>>(cnt, cursor, N);
        csr_fill<<<dim3((E + 255) / 256), 256, 0, stream>>>(receivers, cursor, eList, E);
    }

    const dim3 gE(E / 128);                 // NW=4 edge kernels: 1250 blocks
    const dim3 gN2((N + 63) / 64);          // NW=2 node kernels: 313 blocks
    const dim3 gE4 = gE;

    // ---- encoders ----
    gnn_mlp<2><<<gN2, 128, 0, stream>>>(wt + o_encn[0], 32, wt + o_encn[1], wt + o_encn[2],
        enc_n_b0, enc_n_b1, enc_n_b2, enc_n_g, enc_n_be,
        node_x, 12, nullptr, nullptr, nullptr, nullptr, nullptr, nullptr,
        nf, nfbf, nullptr, nullptr, N, 0, 0);
    gnn_mlp<4><<<gE4, 256, 0, stream>>>(wt + o_ence[0], 32, wt + o_ence[1], wt + o_ence[2],
        enc_e_b0, enc_e_b1, enc_e_b2, enc_e_g, enc_e_be,
        edge_x, 7, nullptr, nullptr, nullptr, nullptr, nullptr, nullptr,
        ef, nullptr, nullptr, nullptr, E, 0, 0);

    // ---- 3 message-passing steps ----
    for (int s = 0; s < 3; ++s) {
        const float* eb0 = gnb_e_b0 + (size_t)s * 128;
        const float* eb1 = gnb_e_b1 + (size_t)s * 128;
        const float* eb2 = gnb_e_b2 + (size_t)s * 128;
        const float* eg  = gnb_e_g  + (size_t)s * 128;
        const float* ebe = gnb_e_be + (size_t)s * 128;
        const float* nb0 = gnb_n_b0 + (size_t)s * 128;
        const float* nb1 = gnb_n_b1 + (size_t)s * 128;
        const float* nb2 = gnb_n_b2 + (size_t)s * 128;
        const float* ng  = gnb_n_g  + (size_t)s * 128;
        const float* nbe = gnb_n_be + (size_t)s * 128;

        zero_kernel<<<dim3((N * 32 + 255) / 256), 256, 0, stream>>>((float4*)agg, (long)N * 32);
        gnn_mlp<4><<<gE, 256, 0, stream>>>(wt + o_ge0[s], 384, wt + o_ge1[s], wt + o_ge2[s],
            eb0, eb1, eb2, eg, ebe,
            nullptr, 0, nfbf, ef, nullptr, eL, senders, receivers,
            ef, nullptr, agg, nullptr, E, 1, 1);
        gnn_mlp<2><<<gN2, 128, 0, stream>>>(wt + o_gn0[s], 256, wt + o_gn1[s], wt + o_gn2[s],
            nb0, nb1, nb2, ng, nbe,
            nullptr, 0, nfbf, nullptr, agg, nullptr, nullptr, nullptr,
            nf, nfbf, nullptr, nullptr, N, 2, 1);
    }

    // ---- decoder ----
    gnn_mlp<2><<<gN2, 128, 0, stream>>>(wt + o_dec[0], 128, wt + o_dec[1], nullptr,
        dec_b0, dec_b1, dec_b2, nullptr, nullptr,
        dec_W2, 0, nfbf, nullptr, nullptr, nullptr, nullptr, nullptr,
        nullptr, nullptr, nullptr, out, N, 3, 0);
}

// Round 12
// 707.990 us; speedup vs baseline: 1.2335x; 1.0273x over previous
//
#include <hip/hip_runtime.h>
#include <hip/hip_bf16.h>

#define NN 20000
#define EE 160000

typedef __attribute__((ext_vector_type(8))) short bf16x8;
typedef __attribute__((ext_vector_type(4))) float f32x4;

__device__ __forceinline__ unsigned short f2bf(float f) {
    unsigned int u = __float_as_uint(f);
    u += 0x7FFFu + ((u >> 16) & 1);   // RNE
    return (unsigned short)(u >> 16);
}
__device__ __forceinline__ float bf2f(short s) {
    return __uint_as_float(((unsigned int)(unsigned short)s) << 16);
}
__device__ __forceinline__ bf16x8 pack8(float4 a, float4 b) {
    bf16x8 r;
    r[0] = (short)f2bf(a.x); r[1] = (short)f2bf(a.y);
    r[2] = (short)f2bf(a.z); r[3] = (short)f2bf(a.w);
    r[4] = (short)f2bf(b.x); r[5] = (short)f2bf(b.y);
    r[6] = (short)f2bf(b.z); r[7] = (short)f2bf(b.w);
    return r;
}

#define SH_STRIDE 136
#define SW_STRIDE 56

// barrier that does NOT drain vmcnt (gathers stay in flight)
__device__ __forceinline__ void bar_lgkm() {
    asm volatile("s_waitcnt lgkmcnt(0)\n\ts_barrier" ::: "memory");
}

__device__ __forceinline__ void mfma_sweep_lds(f32x4 (&acc)[2][8], bf16x8 a0, bf16x8 a1,
                                               const short* sWb, int lm, int lq)
{
#pragma unroll
    for (int ct = 0; ct < 8; ++ct) {
        bf16x8 b = *(const bf16x8*)(sWb + (ct * 16 + lm) * SW_STRIDE + lq * 8);
        acc[0][ct] = __builtin_amdgcn_mfma_f32_16x16x32_bf16(a0, b, acc[0][ct], 0, 0, 0);
        acc[1][ct] = __builtin_amdgcn_mfma_f32_16x16x32_bf16(a1, b, acc[1][ct], 0, 0, 0);
    }
}

template<int NT>
__device__ __forceinline__ void stage_w(short* __restrict__ sW, const short* __restrict__ Wt,
                                        int Kpad, int k0, int tid)
{
    for (int i = tid; i < 256; i += NT) {
        int r = i >> 1, h = i & 1;
        const short* src = Wt + (size_t)r * Kpad + k0 + h * 16;
        short* dst = sW + r * SW_STRIDE + h * 16;
        *(bf16x8*)dst       = *(const bf16x8*)src;
        *(bf16x8*)(dst + 8) = *(const bf16x8*)(src + 8);
    }
}

__device__ __forceinline__ void zero_acc(f32x4 (&acc)[2][8]) {
#pragma unroll
    for (int i = 0; i < 2; ++i)
#pragma unroll
        for (int j = 0; j < 8; ++j) acc[i][j] = (f32x4)(0.f);
}

__device__ __forceinline__ void park(const f32x4 (&acc)[2][8], const float* __restrict__ bias,
                                     short* __restrict__ sH, int w32, int lm, int lq)
{
#pragma unroll
    for (int ct = 0; ct < 8; ++ct) {
        float bb = bias[ct * 16 + lm];
#pragma unroll
        for (int rt = 0; rt < 2; ++rt) {
            int rbase = w32 + rt * 16 + lq * 4;
#pragma unroll
            for (int reg = 0; reg < 4; ++reg) {
                float v = fmaxf(acc[rt][ct][reg] + bb, 0.f);
                sH[(rbase + reg) * SH_STRIDE + ct * 16 + lm] = (short)f2bf(v);
            }
        }
    }
}

struct Frag {
    bf16x8 a0, a1;
    float4 f0, f1, f2, f3;
    int isF;
};

__device__ __forceinline__ void load_frag(Frag& fr, int c, int mode,
    const short* __restrict__ nfb, const float* __restrict__ eff,
    const float* __restrict__ aggf,
    int iS0, int iS1, int iR0, int iR1, size_t eO0, size_t eO1,
    int r0m, int r1m, const short* sH, int w32, int lm, int lq)
{
    int kq = lq * 8;
    fr.isF = 0;
    if (mode == 0) {
        fr.a0 = *(const bf16x8*)&sH[(w32 + lm) * SH_STRIDE + c * 32 + kq];
        fr.a1 = *(const bf16x8*)&sH[(w32 + 16 + lm) * SH_STRIDE + c * 32 + kq];
    } else if (mode == 1) {
        int seg = c >> 2, kb = (c & 3) * 32 + kq;
        if (seg == 0) {
            fr.a0 = *(const bf16x8*)(nfb + (size_t)iS0 * 128 + kb);
            fr.a1 = *(const bf16x8*)(nfb + (size_t)iS1 * 128 + kb);
        } else if (seg == 1) {
            fr.a0 = *(const bf16x8*)(nfb + (size_t)iR0 * 128 + kb);
            fr.a1 = *(const bf16x8*)(nfb + (size_t)iR1 * 128 + kb);
        } else {
            const float* p0 = eff + eO0 + kb;      // slot-contiguous (ef stored sorted)
            const float* p1 = eff + eO1 + kb;
            fr.f0 = *(const float4*)p0; fr.f1 = *(const float4*)(p0 + 4);
            fr.f2 = *(const float4*)p1; fr.f3 = *(const float4*)(p1 + 4);
            fr.isF = 1;
        }
    } else if (mode == 2) {
        int seg = c >> 2, kb = (c & 3) * 32 + kq;
        if (seg == 0) {
            fr.a0 = *(const bf16x8*)(nfb + (size_t)r0m * 128 + kb);
            fr.a1 = *(const bf16x8*)(nfb + (size_t)r1m * 128 + kb);
        } else {
            const float* p0 = aggf + (size_t)r0m * 128 + kb;
            const float* p1 = aggf + (size_t)r1m * 128 + kb;
            fr.f0 = *(const float4*)p0; fr.f1 = *(const float4*)(p0 + 4);
            fr.f2 = *(const float4*)p1; fr.f3 = *(const float4*)(p1 + 4);
            fr.isF = 1;
        }
    } else {
        int kb = c * 32 + kq;
        fr.a0 = *(const bf16x8*)(nfb + (size_t)r0m * 128 + kb);
        fr.a1 = *(const bf16x8*)(nfb + (size_t)r1m * 128 + kb);
    }
}

// NW waves per block, 32 rows per wave.
// modes: 0 encoder (eList = optional src-row gather map); 1 edge (sorted slots,
//        ef stored in SLOT order); 2 node (zeroes own agg rows after reading);
//        3 decoder
template<int NW>
__global__ __launch_bounds__(NW * 64) void gnn_mlp(
    const short* __restrict__ Wt0, int Kpad0,
    const short* __restrict__ Wt1, const short* __restrict__ Wt2,
    const float* __restrict__ b0, const float* __restrict__ b1, const float* __restrict__ b2,
    const float* __restrict__ g, const float* __restrict__ be,
    const float* __restrict__ A0f, int K0,
    const short* __restrict__ nfb,
    const float* __restrict__ eff,
    const float* __restrict__ aggf,
    const int* __restrict__ eList,
    const int* __restrict__ senders, const int* __restrict__ receivers,
    float* __restrict__ outF, short* __restrict__ outB,
    float* __restrict__ aggOut,
    float* __restrict__ decOut,
    int M, int mode, int resid)
{
    __shared__ short sH[NW * 32 * SH_STRIDE];
    __shared__ short sW[128 * SW_STRIDE];
    __shared__ int sRcv[NW * 32], sSnd[NW * 32];
    const int tid = threadIdx.x;
    const int lane = tid & 63;
    const int w = tid >> 6;
    const int lm = lane & 15;
    const int lq = lane >> 4;
    const int w32 = w * 32;
    const int m0 = blockIdx.x * (NW * 32);

    if (mode == 1) {
        if (tid < NW * 32) {
            int slot = m0 + tid;                       // grid exact: slot < E
            int e = eList ? eList[slot] : slot;
            sRcv[tid] = receivers[e];
            sSnd[tid] = senders[e];
        }
        bar_lgkm();
    }

    f32x4 acc[2][8];
    zero_acc(acc);

    // -------- layer 0 (pipelined, lgkm-only barriers) --------
    if (mode == 0) {
#pragma unroll
        for (int i = 0; i < 16; ++i) {
            int flat = lane + i * 64;
            int r = flat >> 5, k = flat & 31;
            int row = m0 + w32 + r;
            float v = 0.f;
            if (k < K0 && row < M) {
                int src = eList ? eList[row] : row;    // gather source rows (sorted write)
                v = A0f[(size_t)src * K0 + k];
            }
            sH[(w32 + r) * SH_STRIDE + k] = (short)f2bf(v);
        }
    }
    int iS0 = 0, iS1 = 0, iR0 = 0, iR1 = 0;
    size_t eO0 = 0, eO1 = 0;
    if (mode == 1) {
        // rt-interleaved: MFMA row m of tile rt <-> sorted slot w32 + 2*m + rt.
        int s0 = w32 + 2 * lm, s1 = s0 + 1;
        iS0 = sSnd[s0]; iS1 = sSnd[s1];
        iR0 = sRcv[s0]; iR1 = sRcv[s1];
        eO0 = (size_t)(m0 + s0) * 128;                 // ef is slot-ordered: contiguous
        eO1 = (size_t)(m0 + s1) * 128;
    }
    const int r0m = min(m0 + w32 + lm, M - 1);
    const int r1m = min(m0 + w32 + 16 + lm, M - 1);
    const int nC0 = Kpad0 >> 5;

    {
        Frag cur, nxt;
        load_frag(cur, 0, mode, nfb, eff, aggf, iS0, iS1, iR0, iR1, eO0, eO1,
                  r0m, r1m, sH, w32, lm, lq);
        for (int c = 0; c < nC0; ++c) {
            if (c + 1 < nC0)
                load_frag(nxt, c + 1, mode, nfb, eff, aggf, iS0, iS1, iR0, iR1, eO0, eO1,
                          r0m, r1m, sH, w32, lm, lq);
            bar_lgkm();
            stage_w<NW * 64>(sW, Wt0, Kpad0, c * 32, tid);
            bar_lgkm();
            bf16x8 u0, u1;
            if (cur.isF) { u0 = pack8(cur.f0, cur.f1); u1 = pack8(cur.f2, cur.f3); }
            else         { u0 = cur.a0;               u1 = cur.a1; }
            mfma_sweep_lds(acc, u0, u1, sW, lm, lq);
            cur = nxt;
        }
    }
    bar_lgkm();
    park(acc, b0, sH, w32, lm, lq);

    // node mode: zero this block's agg rows (all reads consumed above).
    // Clamped re-readers of row M-1 only feed discarded padding outputs.
    if (mode == 2 && aggOut) {
        int totalF4 = NW * 32 * 32;
        for (int i = tid; i < totalF4; i += NW * 64) {
            int r = i >> 5, c4 = i & 31;
            int row = m0 + r;
            if (row < M)
                *(float4*)(aggOut + (size_t)row * 128 + c4 * 4) = make_float4(0.f, 0.f, 0.f, 0.f);
        }
    }

    // -------- layer 1 --------
    zero_acc(acc);
    for (int c = 0; c < 4; ++c) {
        bf16x8 a0 = *(const bf16x8*)&sH[(w32 + lm) * SH_STRIDE + c * 32 + lq * 8];
        bf16x8 a1 = *(const bf16x8*)&sH[(w32 + 16 + lm) * SH_STRIDE + c * 32 + lq * 8];
        bar_lgkm();
        stage_w<NW * 64>(sW, Wt1, 128, c * 32, tid);
        bar_lgkm();
        mfma_sweep_lds(acc, a0, a1, sW, lm, lq);
    }
    bar_lgkm();
    park(acc, b1, sH, w32, lm, lq);

    // -------- decoder tail --------
    if (mode == 3) {
#pragma unroll
        for (int t = 0; t < 2; ++t) {
            int idx = t * 64 + lane;
            if (idx < 96) {
                int r = idx / 3, o = idx - r * 3;
                int row = m0 + w32 + r;
                if (row < M) {
                    float s = b2[o];
#pragma unroll
                    for (int kk = 0; kk < 16; ++kk) {
                        bf16x8 h8 = *(const bf16x8*)&sH[(w32 + r) * SH_STRIDE + kk * 8];
#pragma unroll
                        for (int j = 0; j < 8; ++j)
                            s += bf2f(h8[j]) * A0f[(kk * 8 + j) * 3 + o];
                    }
                    decOut[(size_t)row * 3 + o] = s;
                }
            }
        }
        return;
    }

    // -------- layer 2 --------
    zero_acc(acc);
    for (int c = 0; c < 4; ++c) {
        bf16x8 a0 = *(const bf16x8*)&sH[(w32 + lm) * SH_STRIDE + c * 32 + lq * 8];
        bf16x8 a1 = *(const bf16x8*)&sH[(w32 + 16 + lm) * SH_STRIDE + c * 32 + lq * 8];
        bar_lgkm();
        stage_w<NW * 64>(sW, Wt2, 128, c * 32, tid);
        bar_lgkm();
        mfma_sweep_lds(acc, a0, a1, sW, lm, lq);
    }

    // -------- epilogue --------
    float g_[8], be_[8], b2_[8];
#pragma unroll
    for (int ct = 0; ct < 8; ++ct) {
        g_[ct] = g[ct * 16 + lm]; be_[ct] = be[ct * 16 + lm]; b2_[ct] = b2[ct * 16 + lm];
    }

    if (mode == 1) {
        // lane's 8 C-rows are 8 CONSECUTIVE sorted slots: one merge run;
        // ef residual written at slot position (contiguous stream)
        float run[8];
        int curRcv = -1;
#pragma unroll
        for (int j = 0; j < 8; ++j) {
            int rt = j & 1, reg = j >> 1;
            int rloc = w32 + lq * 8 + j;
            float v[8];
            float s = 0.f;
#pragma unroll
            for (int ct = 0; ct < 8; ++ct) { v[ct] = acc[rt][ct][reg] + b2_[ct]; s += v[ct]; }
            s += __shfl_xor(s, 1); s += __shfl_xor(s, 2);
            s += __shfl_xor(s, 4); s += __shfl_xor(s, 8);
            float mu = s * (1.f / 128.f);
            float q = 0.f;
#pragma unroll
            for (int ct = 0; ct < 8; ++ct) { v[ct] -= mu; q += v[ct] * v[ct]; }
            q += __shfl_xor(q, 1); q += __shfl_xor(q, 2);
            q += __shfl_xor(q, 4); q += __shfl_xor(q, 8);
            float rs = rsqrtf(q * (1.f / 128.f) + 1e-5f);
            int rcv = sRcv[rloc];
            float o[8];
#pragma unroll
            for (int ct = 0; ct < 8; ++ct) {
                o[ct] = v[ct] * rs * g_[ct] + be_[ct];
                size_t gi = (size_t)(m0 + rloc) * 128 + ct * 16 + lm;
                outF[gi] += o[ct];                      // ef residual, slot-ordered
            }
            if (rcv != curRcv) {
                if (curRcv >= 0) {
#pragma unroll
                    for (int ct = 0; ct < 8; ++ct)
                        atomicAdd(aggOut + (size_t)curRcv * 128 + ct * 16 + lm, run[ct]);
                }
                curRcv = rcv;
#pragma unroll
                for (int ct = 0; ct < 8; ++ct) run[ct] = o[ct];
            } else {
#pragma unroll
                for (int ct = 0; ct < 8; ++ct) run[ct] += o[ct];
            }
        }
        if (curRcv >= 0) {
#pragma unroll
            for (int ct = 0; ct < 8; ++ct)
                atomicAdd(aggOut + (size_t)curRcv * 128 + ct * 16 + lm, run[ct]);
        }
    } else {
#pragma unroll
        for (int rt = 0; rt < 2; ++rt) {
#pragma unroll
            for (int reg = 0; reg < 4; ++reg) {
                int row = m0 + w32 + rt * 16 + lq * 4 + reg;
                float v[8];
                float s = 0.f;
#pragma unroll
                for (int ct = 0; ct < 8; ++ct) { v[ct] = acc[rt][ct][reg] + b2_[ct]; s += v[ct]; }
                s += __shfl_xor(s, 1); s += __shfl_xor(s, 2);
                s += __shfl_xor(s, 4); s += __shfl_xor(s, 8);
                float mu = s * (1.f / 128.f);
                float q = 0.f;
#pragma unroll
                for (int ct = 0; ct < 8; ++ct) { v[ct] -= mu; q += v[ct] * v[ct]; }
                q += __shfl_xor(q, 1); q += __shfl_xor(q, 2);
                q += __shfl_xor(q, 4); q += __shfl_xor(q, 8);
                float rs = rsqrtf(q * (1.f / 128.f) + 1e-5f);
                if (row < M) {
#pragma unroll
                    for (int ct = 0; ct < 8; ++ct) {
                        float o = v[ct] * rs * g_[ct] + be_[ct];
                        size_t gi = (size_t)row * 128 + ct * 16 + lm;
                        if (resid) {
                            float ns = outF[gi] + o;
                            outF[gi] = ns;
                            if (outB) outB[gi] = (short)f2bf(ns);
                        } else {
                            outF[gi] = o;
                            if (outB) outB[gi] = (short)f2bf(o);
                        }
                    }
                }
            }
        }
    }
}

// ---------------------------------------------------------------------------
__global__ void zero_i(int* __restrict__ p, int n)
{
    int i = blockIdx.x * 256 + threadIdx.x;
    if (i < n) p[i] = 0;
}
__global__ void csr_count(const int* __restrict__ recv, int* __restrict__ cnt, int E)
{
    int i = blockIdx.x * 256 + threadIdx.x;
    if (i < E) atomicAdd(&cnt[recv[i]], 1);
}
__global__ __launch_bounds__(256) void csr_scan(const int* __restrict__ cnt,
                                                int* __restrict__ cursor, int N)
{
    __shared__ int ssum[257];
    const int tid = threadIdx.x;
    const int per = (N + 255) / 256;
    const int lo = tid * per, hi = min(lo + per, N);
    int s = 0;
    for (int i = lo; i < hi; ++i) s += cnt[i];
    ssum[tid] = s;
    __syncthreads();
    if (tid == 0) {
        int run = 0;
        for (int i = 0; i < 256; ++i) { int t = ssum[i]; ssum[i] = run; run += t; }
        ssum[256] = run;
    }
    __syncthreads();
    int run = ssum[tid];
    for (int i = lo; i < hi; ++i) { int c = cnt[i]; cursor[i] = run; run += c; }
}
__global__ void csr_fill(const int* __restrict__ recv, int* __restrict__ cursor,
                         int* __restrict__ eList, int E)
{
    int i = blockIdx.x * 256 + threadIdx.x;
    if (i < E) {
        int pos = atomicAdd(&cursor[recv[i]], 1);
        eList[pos] = i;
    }
}

// ---------------------------------------------------------------------------
struct WtPrep { const float* src; int K; int Kpad; int dstOff; };
struct WtPrepAll { WtPrep m[26]; };

__global__ void wt_prep_kernel(WtPrepAll all, short* __restrict__ dst)
{
    const WtPrep p = all.m[blockIdx.y];
    int total = 128 * p.Kpad;
    int idx = blockIdx.x * 256 + threadIdx.x;
    if (idx >= total) return;
    int n = idx / p.Kpad, k = idx - n * p.Kpad;
    float v = (k < p.K) ? p.src[(size_t)k * 128 + n] : 0.f;
    dst[p.dstOff + idx] = (short)f2bf(v);
}

__global__ void zero_kernel(float4* __restrict__ p, long n4)
{
    long i = (long)blockIdx.x * blockDim.x + threadIdx.x;
    if (i < n4) p[i] = make_float4(0.f, 0.f, 0.f, 0.f);
}

// ---------------------------------------------------------------------------
extern "C" void kernel_launch(void* const* d_in, const int* in_sizes, int n_in,
                              void* d_out, int out_size, void* d_ws, size_t ws_size,
                              hipStream_t stream)
{
    const float* node_x   = (const float*)d_in[0];
    const float* edge_x   = (const float*)d_in[1];
    const float* enc_n_W0 = (const float*)d_in[2];
    const float* enc_n_b0 = (const float*)d_in[3];
    const float* enc_n_W1 = (const float*)d_in[4];
    const float* enc_n_b1 = (const float*)d_in[5];
    const float* enc_n_W2 = (const float*)d_in[6];
    const float* enc_n_b2 = (const float*)d_in[7];
    const float* enc_n_g  = (const float*)d_in[8];
    const float* enc_n_be = (const float*)d_in[9];
    const float* enc_e_W0 = (const float*)d_in[10];
    const float* enc_e_b0 = (const float*)d_in[11];
    const float* enc_e_W1 = (const float*)d_in[12];
    const float* enc_e_b1 = (const float*)d_in[13];
    const float* enc_e_W2 = (const float*)d_in[14];
    const float* enc_e_b2 = (const float*)d_in[15];
    const float* enc_e_g  = (const float*)d_in[16];
    const float* enc_e_be = (const float*)d_in[17];
    const float* gnb_e_W0 = (const float*)d_in[18];
    const float* gnb_e_b0 = (const float*)d_in[19];
    const float* gnb_e_W1 = (const float*)d_in[20];
    const float* gnb_e_b1 = (const float*)d_in[21];
    const float* gnb_e_W2 = (const float*)d_in[22];
    const float* gnb_e_b2 = (const float*)d_in[23];
    const float* gnb_e_g  = (const float*)d_in[24];
    const float* gnb_e_be = (const float*)d_in[25];
    const float* gnb_n_W0 = (const float*)d_in[26];
    const float* gnb_n_b0 = (const float*)d_in[27];
    const float* gnb_n_W1 = (const float*)d_in[28];
    const float* gnb_n_b1 = (const float*)d_in[29];
    const float* gnb_n_W2 = (const float*)d_in[30];
    const float* gnb_n_b2 = (const float*)d_in[31];
    const float* gnb_n_g  = (const float*)d_in[32];
    const float* gnb_n_be = (const float*)d_in[33];
    const float* dec_W0   = (const float*)d_in[34];
    const float* dec_b0   = (const float*)d_in[35];
    const float* dec_W1   = (const float*)d_in[36];
    const float* dec_b1   = (const float*)d_in[37];
    const float* dec_W2   = (const float*)d_in[38];
    const float* dec_b2   = (const float*)d_in[39];
    const int*   senders  = (const int*)d_in[40];
    const int*   receivers= (const int*)d_in[41];
    float* out = (float*)d_out;

    const int N = NN, E = EE;
    const int WT_TOTAL = (32 + 128 + 128 + 32 + 128 + 128 + 3 * (384 + 128 + 128 + 256 + 128 + 128)
                          + 128 + 128) * 128;

    // ---- workspace layout: identical to round 6/8/10/11 (109.26 MB, known-good) ----
    float* nf   = (float*)d_ws;
    float* agg  = nf + (size_t)N * 128;
    float* ef   = agg + (size_t)N * 128;     // stored in SORTED-SLOT order
    short* nfbf = (short*)(ef + (size_t)E * 128);
    short* wt   = nfbf + (size_t)N * 128;
    int*   eList = (int*)(wt + WT_TOTAL);
    size_t need_sorted = (size_t)((char*)(eList + E) - (char*)d_ws);
    int* cnt    = (int*)agg;
    int* cursor = cnt + N;

    const bool useSorted = (ws_size >= need_sorted);
    const int* eL = useSorted ? eList : nullptr;

    WtPrepAll tbl;
    int nMat = 0, off = 0;
    int o_encn[3], o_ence[3], o_ge0[3], o_ge1[3], o_ge2[3], o_gn0[3], o_gn1[3], o_gn2[3], o_dec[2];
    auto add = [&](const float* src, int K, int Kpad) {
        tbl.m[nMat].src = src; tbl.m[nMat].K = K; tbl.m[nMat].Kpad = Kpad;
        tbl.m[nMat].dstOff = off;
        int r = off; off += 128 * Kpad; ++nMat; return r;
    };
    o_encn[0] = add(enc_n_W0, 12, 32);
    o_encn[1] = add(enc_n_W1, 128, 128);
    o_encn[2] = add(enc_n_W2, 128, 128);
    o_ence[0] = add(enc_e_W0, 7, 32);
    o_ence[1] = add(enc_e_W1, 128, 128);
    o_ence[2] = add(enc_e_W2, 128, 128);
    for (int s = 0; s < 3; ++s) {
        o_ge0[s] = add(gnb_e_W0 + (size_t)s * 384 * 128, 384, 384);
        o_ge1[s] = add(gnb_e_W1 + (size_t)s * 128 * 128, 128, 128);
        o_ge2[s] = add(gnb_e_W2 + (size_t)s * 128 * 128, 128, 128);
        o_gn0[s] = add(gnb_n_W0 + (size_t)s * 256 * 128, 256, 256);
        o_gn1[s] = add(gnb_n_W1 + (size_t)s * 128 * 128, 128, 128);
        o_gn2[s] = add(gnb_n_W2 + (size_t)s * 128 * 128, 128, 128);
    }
    o_dec[0] = add(dec_W0, 128, 128);
    o_dec[1] = add(dec_W1, 128, 128);

    wt_prep_kernel<<<dim3(192, 26), 256, 0, stream>>>(tbl, wt);

    if (useSorted) {
        zero_i<<<dim3((N + 255) / 256), 256, 0, stream>>>(cnt, N);
        csr_count<<<dim3((E + 255) / 256), 256, 0, stream>>>(receivers, cnt, E);
        csr_scan<<<dim3(1), 256, 0, stream>>>(cnt, cursor, N);
        csr_fill<<<dim3((E + 255) / 256), 256, 0, stream>>>(receivers, cursor, eList, E);
    }
    // zero agg once (after csr: cnt/cursor overlay agg); steps re-zero in node kernel
    zero_kernel<<<dim3((N * 32 + 255) / 256), 256, 0, stream>>>((float4*)agg, (long)N * 32);

    const dim3 gE(E / 128);                 // NW=4 edge kernels: 1250 blocks
    const dim3 gN2((N + 63) / 64);          // NW=2 node kernels: 313 blocks

    // ---- encoders ----
    gnn_mlp<2><<<gN2, 128, 0, stream>>>(wt + o_encn[0], 32, wt + o_encn[1], wt + o_encn[2],
        enc_n_b0, enc_n_b1, enc_n_b2, enc_n_g, enc_n_be,
        node_x, 12, nullptr, nullptr, nullptr, nullptr, nullptr, nullptr,
        nf, nfbf, nullptr, nullptr, N, 0, 0);
    // edge encoder gathers edge_x[eList[slot]] so ef lands in slot order
    gnn_mlp<4><<<gE, 256, 0, stream>>>(wt + o_ence[0], 32, wt + o_ence[1], wt + o_ence[2],
        enc_e_b0, enc_e_b1, enc_e_b2, enc_e_g, enc_e_be,
        edge_x, 7, nullptr, nullptr, nullptr, eL, nullptr, nullptr,
        ef, nullptr, nullptr, nullptr, E, 0, 0);

    // ---- 3 message-passing steps ----
    for (int s = 0; s < 3; ++s) {
        const float* eb0 = gnb_e_b0 + (size_t)s * 128;
        const float* eb1 = gnb_e_b1 + (size_t)s * 128;
        const float* eb2 = gnb_e_b2 + (size_t)s * 128;
        const float* eg  = gnb_e_g  + (size_t)s * 128;
        const float* ebe = gnb_e_be + (size_t)s * 128;
        const float* nb0 = gnb_n_b0 + (size_t)s * 128;
        const float* nb1 = gnb_n_b1 + (size_t)s * 128;
        const float* nb2 = gnb_n_b2 + (size_t)s * 128;
        const float* ng  = gnb_n_g  + (size_t)s * 128;
        const float* nbe = gnb_n_be + (size_t)s * 128;

        gnn_mlp<4><<<gE, 256, 0, stream>>>(wt + o_ge0[s], 384, wt + o_ge1[s], wt + o_ge2[s],
            eb0, eb1, eb2, eg, ebe,
            nullptr, 0, nfbf, ef, nullptr, eL, senders, receivers,
            ef, nullptr, agg, nullptr, E, 1, 1);
        gnn_mlp<2><<<gN2, 128, 0, stream>>>(wt + o_gn0[s], 256, wt + o_gn1[s], wt + o_gn2[s],
            nb0, nb1, nb2, ng, nbe,
            nullptr, 0, nfbf, nullptr, agg, nullptr, nullptr, nullptr,
            nf, nfbf, agg, nullptr, N, 2, 1);
    }

    // ---- decoder ----
    gnn_mlp<2><<<gN2, 128, 0, stream>>>(wt + o_dec[0], 128, wt + o_dec[1], nullptr,
        dec_b0, dec_b1, dec_b2, nullptr, nullptr,
        dec_W2, 0, nfbf, nullptr, nullptr, nullptr, nullptr, nullptr,
        nullptr, nullptr, nullptr, out, N, 3, 0);
}

// Round 13
// 664.015 us; speedup vs baseline: 1.3152x; 1.0662x over previous
//
#include <hip/hip_runtime.h>
#include <hip/hip_bf16.h>

#define NN 20000
#define EE 160000

typedef __attribute__((ext_vector_type(8))) short bf16x8;
typedef __attribute__((ext_vector_type(4))) float f32x4;

__device__ __forceinline__ unsigned short f2bf(float f) {
    unsigned int u = __float_as_uint(f);
    u += 0x7FFFu + ((u >> 16) & 1);   // RNE
    return (unsigned short)(u >> 16);
}
__device__ __forceinline__ float bf2f(short s) {
    return __uint_as_float(((unsigned int)(unsigned short)s) << 16);
}
__device__ __forceinline__ bf16x8 pack8(float4 a, float4 b) {
    bf16x8 r;
    r[0] = (short)f2bf(a.x); r[1] = (short)f2bf(a.y);
    r[2] = (short)f2bf(a.z); r[3] = (short)f2bf(a.w);
    r[4] = (short)f2bf(b.x); r[5] = (short)f2bf(b.y);
    r[6] = (short)f2bf(b.z); r[7] = (short)f2bf(b.w);
    return r;
}

#define SH_STRIDE 136
#define SW_STRIDE 56

// barrier that does NOT drain vmcnt (gathers stay in flight)
__device__ __forceinline__ void bar_lgkm() {
    asm volatile("s_waitcnt lgkmcnt(0)\n\ts_barrier" ::: "memory");
}

__device__ __forceinline__ void mfma_sweep_lds(f32x4 (&acc)[2][8], bf16x8 a0, bf16x8 a1,
                                               const short* sWb, int lm, int lq)
{
#pragma unroll
    for (int ct = 0; ct < 8; ++ct) {
        bf16x8 b = *(const bf16x8*)(sWb + (ct * 16 + lm) * SW_STRIDE + lq * 8);
        acc[0][ct] = __builtin_amdgcn_mfma_f32_16x16x32_bf16(a0, b, acc[0][ct], 0, 0, 0);
        acc[1][ct] = __builtin_amdgcn_mfma_f32_16x16x32_bf16(a1, b, acc[1][ct], 0, 0, 0);
    }
}

// W-chunk pipeline: load (registers, issued early) / store (ds_write, later).
// Splitting these lets the ds_write's vmcnt wait target ONLY the old chunk's
// loads; newer prefetch loads (W(c+1), gathers) stay in flight (vmcnt retires
// in issue order on CDNA).
template<int NT>
struct WStage { bf16x8 v[512 / NT]; };

template<int NT>
__device__ __forceinline__ void wload(WStage<NT>& ws, const short* __restrict__ Wt,
                                      int Kpad, int k0, int tid)
{
#pragma unroll
    for (int j = 0; j < 256 / NT; ++j) {
        int i = tid + j * NT;
        int r = i >> 1, h = i & 1;
        const short* src = Wt + (size_t)r * Kpad + k0 + h * 16;
        ws.v[2 * j]     = *(const bf16x8*)src;
        ws.v[2 * j + 1] = *(const bf16x8*)(src + 8);
    }
}
template<int NT>
__device__ __forceinline__ void wstore(const WStage<NT>& ws, short* __restrict__ sW, int tid)
{
#pragma unroll
    for (int j = 0; j < 256 / NT; ++j) {
        int i = tid + j * NT;
        int r = i >> 1, h = i & 1;
        short* dst = sW + r * SW_STRIDE + h * 16;
        *(bf16x8*)dst       = ws.v[2 * j];
        *(bf16x8*)(dst + 8) = ws.v[2 * j + 1];
    }
}

__device__ __forceinline__ void zero_acc(f32x4 (&acc)[2][8]) {
#pragma unroll
    for (int i = 0; i < 2; ++i)
#pragma unroll
        for (int j = 0; j < 8; ++j) acc[i][j] = (f32x4)(0.f);
}

__device__ __forceinline__ void park(const f32x4 (&acc)[2][8], const float* __restrict__ bias,
                                     short* __restrict__ sH, int w32, int lm, int lq)
{
#pragma unroll
    for (int ct = 0; ct < 8; ++ct) {
        float bb = bias[ct * 16 + lm];
#pragma unroll
        for (int rt = 0; rt < 2; ++rt) {
            int rbase = w32 + rt * 16 + lq * 4;
#pragma unroll
            for (int reg = 0; reg < 4; ++reg) {
                float v = fmaxf(acc[rt][ct][reg] + bb, 0.f);
                sH[(rbase + reg) * SH_STRIDE + ct * 16 + lm] = (short)f2bf(v);
            }
        }
    }
}

struct Frag {
    bf16x8 a0, a1;
    float4 f0, f1, f2, f3;
    int isF;
};

__device__ __forceinline__ void load_frag(Frag& fr, int c, int mode,
    const short* __restrict__ nfb, const float* __restrict__ eff,
    const float* __restrict__ aggf,
    int iS0, int iS1, int iR0, int iR1, size_t eO0, size_t eO1,
    int r0m, int r1m, const short* sH, int w32, int lm, int lq)
{
    int kq = lq * 8;
    fr.isF = 0;
    if (mode == 0) {
        fr.a0 = *(const bf16x8*)&sH[(w32 + lm) * SH_STRIDE + c * 32 + kq];
        fr.a1 = *(const bf16x8*)&sH[(w32 + 16 + lm) * SH_STRIDE + c * 32 + kq];
    } else if (mode == 1) {
        int seg = c >> 2, kb = (c & 3) * 32 + kq;
        if (seg == 0) {
            fr.a0 = *(const bf16x8*)(nfb + (size_t)iS0 * 128 + kb);
            fr.a1 = *(const bf16x8*)(nfb + (size_t)iS1 * 128 + kb);
        } else if (seg == 1) {
            fr.a0 = *(const bf16x8*)(nfb + (size_t)iR0 * 128 + kb);
            fr.a1 = *(const bf16x8*)(nfb + (size_t)iR1 * 128 + kb);
        } else {
            const float* p0 = eff + eO0 + kb;      // slot-contiguous (ef stored sorted)
            const float* p1 = eff + eO1 + kb;
            fr.f0 = *(const float4*)p0; fr.f1 = *(const float4*)(p0 + 4);
            fr.f2 = *(const float4*)p1; fr.f3 = *(const float4*)(p1 + 4);
            fr.isF = 1;
        }
    } else if (mode == 2) {
        int seg = c >> 2, kb = (c & 3) * 32 + kq;
        if (seg == 0) {
            fr.a0 = *(const bf16x8*)(nfb + (size_t)r0m * 128 + kb);
            fr.a1 = *(const bf16x8*)(nfb + (size_t)r1m * 128 + kb);
        } else {
            const float* p0 = aggf + (size_t)r0m * 128 + kb;
            const float* p1 = aggf + (size_t)r1m * 128 + kb;
            fr.f0 = *(const float4*)p0; fr.f1 = *(const float4*)(p0 + 4);
            fr.f2 = *(const float4*)p1; fr.f3 = *(const float4*)(p1 + 4);
            fr.isF = 1;
        }
    } else {
        int kb = c * 32 + kq;
        fr.a0 = *(const bf16x8*)(nfb + (size_t)r0m * 128 + kb);
        fr.a1 = *(const bf16x8*)(nfb + (size_t)r1m * 128 + kb);
    }
}

// NW waves per block, 32 rows per wave.
// modes: 0 encoder (eList = optional src-row gather map); 1 edge (sorted slots,
//        ef stored in SLOT order); 2 node (zeroes own agg rows after reading);
//        3 decoder
template<int NW>
__global__ __launch_bounds__(NW * 64) void gnn_mlp(
    const short* __restrict__ Wt0, int Kpad0,
    const short* __restrict__ Wt1, const short* __restrict__ Wt2,
    const float* __restrict__ b0, const float* __restrict__ b1, const float* __restrict__ b2,
    const float* __restrict__ g, const float* __restrict__ be,
    const float* __restrict__ A0f, int K0,
    const short* __restrict__ nfb,
    const float* __restrict__ eff,
    const float* __restrict__ aggf,
    const int* __restrict__ eList,
    const int* __restrict__ senders, const int* __restrict__ receivers,
    float* __restrict__ outF, short* __restrict__ outB,
    float* __restrict__ aggOut,
    float* __restrict__ decOut,
    int M, int mode, int resid)
{
    __shared__ short sH[NW * 32 * SH_STRIDE];
    __shared__ short sW[128 * SW_STRIDE];
    __shared__ int sRcv[NW * 32], sSnd[NW * 32];
    const int tid = threadIdx.x;
    const int lane = tid & 63;
    const int w = tid >> 6;
    const int lm = lane & 15;
    const int lq = lane >> 4;
    const int w32 = w * 32;
    const int m0 = blockIdx.x * (NW * 32);
    const int NT = NW * 64;

    if (mode == 1) {
        if (tid < NW * 32) {
            int slot = m0 + tid;                       // grid exact: slot < E
            int e = eList ? eList[slot] : slot;
            sRcv[tid] = receivers[e];
            sSnd[tid] = senders[e];
        }
        bar_lgkm();
    }

    f32x4 acc[2][8];
    zero_acc(acc);

    // -------- layer 0 (true software pipeline: W + gathers one chunk ahead) ----
    if (mode == 0) {
#pragma unroll
        for (int i = 0; i < 16; ++i) {
            int flat = lane + i * 64;
            int r = flat >> 5, k = flat & 31;
            int row = m0 + w32 + r;
            float v = 0.f;
            if (k < K0 && row < M) {
                int src = eList ? eList[row] : row;    // gather source rows (sorted write)
                v = A0f[(size_t)src * K0 + k];
            }
            sH[(w32 + r) * SH_STRIDE + k] = (short)f2bf(v);
        }
    }
    int iS0 = 0, iS1 = 0, iR0 = 0, iR1 = 0;
    size_t eO0 = 0, eO1 = 0;
    if (mode == 1) {
        // rt-interleaved: MFMA row m of tile rt <-> sorted slot w32 + 2*m + rt.
        int s0 = w32 + 2 * lm, s1 = s0 + 1;
        iS0 = sSnd[s0]; iS1 = sSnd[s1];
        iR0 = sRcv[s0]; iR1 = sRcv[s1];
        eO0 = (size_t)(m0 + s0) * 128;                 // ef is slot-ordered: contiguous
        eO1 = (size_t)(m0 + s1) * 128;
    }
    const int r0m = min(m0 + w32 + lm, M - 1);
    const int r1m = min(m0 + w32 + 16 + lm, M - 1);
    const int nC0 = Kpad0 >> 5;

    {
        WStage<NW * 64> ws, wsn;
        Frag cur, nxt;
        wload<NT>(ws, Wt0, Kpad0, 0, tid);             // W(0) first
        load_frag(cur, 0, mode, nfb, eff, aggf, iS0, iS1, iR0, iR1, eO0, eO1,
                  r0m, r1m, sH, w32, lm, lq);
        for (int c = 0; c < nC0; ++c) {
            if (c + 1 < nC0) {
                wload<NT>(wsn, Wt0, Kpad0, (c + 1) * 32, tid);   // W(c+1) BEFORE gathers
                load_frag(nxt, c + 1, mode, nfb, eff, aggf, iS0, iS1, iR0, iR1, eO0, eO1,
                          r0m, r1m, sH, w32, lm, lq);
            }
            bar_lgkm();                 // waves done reading previous sW chunk
            wstore<NT>(ws, sW, tid);    // vmcnt wait targets ws only; wsn+nxt stay in flight
            bar_lgkm();                 // chunk staged
            bf16x8 u0, u1;
            if (cur.isF) { u0 = pack8(cur.f0, cur.f1); u1 = pack8(cur.f2, cur.f3); }
            else         { u0 = cur.a0;               u1 = cur.a1; }
            mfma_sweep_lds(acc, u0, u1, sW, lm, lq);
            ws = wsn; cur = nxt;
        }
    }
    bar_lgkm();
    park(acc, b0, sH, w32, lm, lq);

    // node mode: zero this block's agg rows (all reads consumed above).
    if (mode == 2 && aggOut) {
        int totalF4 = NW * 32 * 32;
        for (int i = tid; i < totalF4; i += NW * 64) {
            int r = i >> 5, c4 = i & 31;
            int row = m0 + r;
            if (row < M)
                *(float4*)(aggOut + (size_t)row * 128 + c4 * 4) = make_float4(0.f, 0.f, 0.f, 0.f);
        }
    }

    // -------- layer 1 (W pipelined) --------
    zero_acc(acc);
    {
        WStage<NW * 64> ws, wsn;
        wload<NT>(ws, Wt1, 128, 0, tid);
        for (int c = 0; c < 4; ++c) {
            if (c + 1 < 4) wload<NT>(wsn, Wt1, 128, (c + 1) * 32, tid);
            bf16x8 a0 = *(const bf16x8*)&sH[(w32 + lm) * SH_STRIDE + c * 32 + lq * 8];
            bf16x8 a1 = *(const bf16x8*)&sH[(w32 + 16 + lm) * SH_STRIDE + c * 32 + lq * 8];
            bar_lgkm();
            wstore<NT>(ws, sW, tid);
            bar_lgkm();
            mfma_sweep_lds(acc, a0, a1, sW, lm, lq);
            ws = wsn;
        }
    }
    bar_lgkm();
    park(acc, b1, sH, w32, lm, lq);

    // -------- decoder tail --------
    if (mode == 3) {
#pragma unroll
        for (int t = 0; t < 2; ++t) {
            int idx = t * 64 + lane;
            if (idx < 96) {
                int r = idx / 3, o = idx - r * 3;
                int row = m0 + w32 + r;
                if (row < M) {
                    float s = b2[o];
#pragma unroll
                    for (int kk = 0; kk < 16; ++kk) {
                        bf16x8 h8 = *(const bf16x8*)&sH[(w32 + r) * SH_STRIDE + kk * 8];
#pragma unroll
                        for (int j = 0; j < 8; ++j)
                            s += bf2f(h8[j]) * A0f[(kk * 8 + j) * 3 + o];
                    }
                    decOut[(size_t)row * 3 + o] = s;
                }
            }
        }
        return;
    }

    // -------- layer 2 (W pipelined) --------
    zero_acc(acc);
    {
        WStage<NW * 64> ws, wsn;
        wload<NT>(ws, Wt2, 128, 0, tid);
        for (int c = 0; c < 4; ++c) {
            if (c + 1 < 4) wload<NT>(wsn, Wt2, 128, (c + 1) * 32, tid);
            bf16x8 a0 = *(const bf16x8*)&sH[(w32 + lm) * SH_STRIDE + c * 32 + lq * 8];
            bf16x8 a1 = *(const bf16x8*)&sH[(w32 + 16 + lm) * SH_STRIDE + c * 32 + lq * 8];
            bar_lgkm();
            wstore<NT>(ws, sW, tid);
            bar_lgkm();
            mfma_sweep_lds(acc, a0, a1, sW, lm, lq);
            ws = wsn;
        }
    }

    // -------- epilogue --------
    float g_[8], be_[8], b2_[8];
#pragma unroll
    for (int ct = 0; ct < 8; ++ct) {
        g_[ct] = g[ct * 16 + lm]; be_[ct] = be[ct * 16 + lm]; b2_[ct] = b2[ct * 16 + lm];
    }

    if (mode == 1) {
        // lane's 8 C-rows are 8 CONSECUTIVE sorted slots: one merge run;
        // ef residual written at slot position (contiguous stream)
        float run[8];
        int curRcv = -1;
#pragma unroll
        for (int j = 0; j < 8; ++j) {
            int rt = j & 1, reg = j >> 1;
            int rloc = w32 + lq * 8 + j;
            float v[8];
            float s = 0.f;
#pragma unroll
            for (int ct = 0; ct < 8; ++ct) { v[ct] = acc[rt][ct][reg] + b2_[ct]; s += v[ct]; }
            s += __shfl_xor(s, 1); s += __shfl_xor(s, 2);
            s += __shfl_xor(s, 4); s += __shfl_xor(s, 8);
            float mu = s * (1.f / 128.f);
            float q = 0.f;
#pragma unroll
            for (int ct = 0; ct < 8; ++ct) { v[ct] -= mu; q += v[ct] * v[ct]; }
            q += __shfl_xor(q, 1); q += __shfl_xor(q, 2);
            q += __shfl_xor(q, 4); q += __shfl_xor(q, 8);
            float rs = rsqrtf(q * (1.f / 128.f) + 1e-5f);
            int rcv = sRcv[rloc];
            float o[8];
#pragma unroll
            for (int ct = 0; ct < 8; ++ct) {
                o[ct] = v[ct] * rs * g_[ct] + be_[ct];
                size_t gi = (size_t)(m0 + rloc) * 128 + ct * 16 + lm;
                outF[gi] += o[ct];                      // ef residual, slot-ordered
            }
            if (rcv != curRcv) {
                if (curRcv >= 0) {
#pragma unroll
                    for (int ct = 0; ct < 8; ++ct)
                        atomicAdd(aggOut + (size_t)curRcv * 128 + ct * 16 + lm, run[ct]);
                }
                curRcv = rcv;
#pragma unroll
                for (int ct = 0; ct < 8; ++ct) run[ct] = o[ct];
            } else {
#pragma unroll
                for (int ct = 0; ct < 8; ++ct) run[ct] += o[ct];
            }
        }
        if (curRcv >= 0) {
#pragma unroll
            for (int ct = 0; ct < 8; ++ct)
                atomicAdd(aggOut + (size_t)curRcv * 128 + ct * 16 + lm, run[ct]);
        }
    } else {
#pragma unroll
        for (int rt = 0; rt < 2; ++rt) {
#pragma unroll
            for (int reg = 0; reg < 4; ++reg) {
                int row = m0 + w32 + rt * 16 + lq * 4 + reg;
                float v[8];
                float s = 0.f;
#pragma unroll
                for (int ct = 0; ct < 8; ++ct) { v[ct] = acc[rt][ct][reg] + b2_[ct]; s += v[ct]; }
                s += __shfl_xor(s, 1); s += __shfl_xor(s, 2);
                s += __shfl_xor(s, 4); s += __shfl_xor(s, 8);
                float mu = s * (1.f / 128.f);
                float q = 0.f;
#pragma unroll
                for (int ct = 0; ct < 8; ++ct) { v[ct] -= mu; q += v[ct] * v[ct]; }
                q += __shfl_xor(q, 1); q += __shfl_xor(q, 2);
                q += __shfl_xor(q, 4); q += __shfl_xor(q, 8);
                float rs = rsqrtf(q * (1.f / 128.f) + 1e-5f);
                if (row < M) {
#pragma unroll
                    for (int ct = 0; ct < 8; ++ct) {
                        float o = v[ct] * rs * g_[ct] + be_[ct];
                        size_t gi = (size_t)row * 128 + ct * 16 + lm;
                        if (resid) {
                            float ns = outF[gi] + o;
                            outF[gi] = ns;
                            if (outB) outB[gi] = (short)f2bf(ns);
                        } else {
                            outF[gi] = o;
                            if (outB) outB[gi] = (short)f2bf(o);
                        }
                    }
                }
            }
        }
    }
}

// ---------------------------------------------------------------------------
__global__ void zero_i(int* __restrict__ p, int n)
{
    int i = blockIdx.x * 256 + threadIdx.x;
    if (i < n) p[i] = 0;
}
__global__ void csr_count(const int* __restrict__ recv, int* __restrict__ cnt, int E)
{
    int i = blockIdx.x * 256 + threadIdx.x;
    if (i < E) atomicAdd(&cnt[recv[i]], 1);
}
__global__ __launch_bounds__(256) void csr_scan(const int* __restrict__ cnt,
                                                int* __restrict__ cursor, int N)
{
    __shared__ int ssum[257];
    const int tid = threadIdx.x;
    const int per = (N + 255) / 256;
    const int lo = tid * per, hi = min(lo + per, N);
    int s = 0;
    for (int i = lo; i < hi; ++i) s += cnt[i];
    ssum[tid] = s;
    __syncthreads();
    if (tid == 0) {
        int run = 0;
        for (int i = 0; i < 256; ++i) { int t = ssum[i]; ssum[i] = run; run += t; }
        ssum[256] = run;
    }
    __syncthreads();
    int run = ssum[tid];
    for (int i = lo; i < hi; ++i) { int c = cnt[i]; cursor[i] = run; run += c; }
}
__global__ void csr_fill(const int* __restrict__ recv, int* __restrict__ cursor,
                         int* __restrict__ eList, int E)
{
    int i = blockIdx.x * 256 + threadIdx.x;
    if (i < E) {
        int pos = atomicAdd(&cursor[recv[i]], 1);
        eList[pos] = i;
    }
}

// ---------------------------------------------------------------------------
struct WtPrep { const float* src; int K; int Kpad; int dstOff; };
struct WtPrepAll { WtPrep m[26]; };

__global__ void wt_prep_kernel(WtPrepAll all, short* __restrict__ dst)
{
    const WtPrep p = all.m[blockIdx.y];
    int total = 128 * p.Kpad;
    int idx = blockIdx.x * 256 + threadIdx.x;
    if (idx >= total) return;
    int n = idx / p.Kpad, k = idx - n * p.Kpad;
    float v = (k < p.K) ? p.src[(size_t)k * 128 + n] : 0.f;
    dst[p.dstOff + idx] = (short)f2bf(v);
}

__global__ void zero_kernel(float4* __restrict__ p, long n4)
{
    long i = (long)blockIdx.x * blockDim.x + threadIdx.x;
    if (i < n4) p[i] = make_float4(0.f, 0.f, 0.f, 0.f);
}

// ---------------------------------------------------------------------------
extern "C" void kernel_launch(void* const* d_in, const int* in_sizes, int n_in,
                              void* d_out, int out_size, void* d_ws, size_t ws_size,
                              hipStream_t stream)
{
    const float* node_x   = (const float*)d_in[0];
    const float* edge_x   = (const float*)d_in[1];
    const float* enc_n_W0 = (const float*)d_in[2];
    const float* enc_n_b0 = (const float*)d_in[3];
    const float* enc_n_W1 = (const float*)d_in[4];
    const float* enc_n_b1 = (const float*)d_in[5];
    const float* enc_n_W2 = (const float*)d_in[6];
    const float* enc_n_b2 = (const float*)d_in[7];
    const float* enc_n_g  = (const float*)d_in[8];
    const float* enc_n_be = (const float*)d_in[9];
    const float* enc_e_W0 = (const float*)d_in[10];
    const float* enc_e_b0 = (const float*)d_in[11];
    const float* enc_e_W1 = (const float*)d_in[12];
    const float* enc_e_b1 = (const float*)d_in[13];
    const float* enc_e_W2 = (const float*)d_in[14];
    const float* enc_e_b2 = (const float*)d_in[15];
    const float* enc_e_g  = (const float*)d_in[16];
    const float* enc_e_be = (const float*)d_in[17];
    const float* gnb_e_W0 = (const float*)d_in[18];
    const float* gnb_e_b0 = (const float*)d_in[19];
    const float* gnb_e_W1 = (const float*)d_in[20];
    const float* gnb_e_b1 = (const float*)d_in[21];
    const float* gnb_e_W2 = (const float*)d_in[22];
    const float* gnb_e_b2 = (const float*)d_in[23];
    const float* gnb_e_g  = (const float*)d_in[24];
    const float* gnb_e_be = (const float*)d_in[25];
    const float* gnb_n_W0 = (const float*)d_in[26];
    const float* gnb_n_b0 = (const float*)d_in[27];
    const float* gnb_n_W1 = (const float*)d_in[28];
    const float* gnb_n_b1 = (const float*)d_in[29];
    const float* gnb_n_W2 = (const float*)d_in[30];
    const float* gnb_n_b2 = (const float*)d_in[31];
    const float* gnb_n_g  = (const float*)d_in[32];
    const float* gnb_n_be = (const float*)d_in[33];
    const float* dec_W0   = (const float*)d_in[34];
    const float* dec_b0   = (const float*)d_in[35];
    const float* dec_W1   = (const float*)d_in[36];
    const float* dec_b1   = (const float*)d_in[37];
    const float* dec_W2   = (const float*)d_in[38];
    const float* dec_b2   = (const float*)d_in[39];
    const int*   senders  = (const int*)d_in[40];
    const int*   receivers= (const int*)d_in[41];
    float* out = (float*)d_out;

    const int N = NN, E = EE;
    const int WT_TOTAL = (32 + 128 + 128 + 32 + 128 + 128 + 3 * (384 + 128 + 128 + 256 + 128 + 128)
                          + 128 + 128) * 128;

    // ---- workspace layout: identical to rounds 6..12 (109.26 MB, known-good) ----
    float* nf   = (float*)d_ws;
    float* agg  = nf + (size_t)N * 128;
    float* ef   = agg + (size_t)N * 128;     // stored in SORTED-SLOT order
    short* nfbf = (short*)(ef + (size_t)E * 128);
    short* wt   = nfbf + (size_t)N * 128;
    int*   eList = (int*)(wt + WT_TOTAL);
    size_t need_sorted = (size_t)((char*)(eList + E) - (char*)d_ws);
    int* cnt    = (int*)agg;
    int* cursor = cnt + N;

    const bool useSorted = (ws_size >= need_sorted);
    const int* eL = useSorted ? eList : nullptr;

    WtPrepAll tbl;
    int nMat = 0, off = 0;
    int o_encn[3], o_ence[3], o_ge0[3], o_ge1[3], o_ge2[3], o_gn0[3], o_gn1[3], o_gn2[3], o_dec[2];
    auto add = [&](const float* src, int K, int Kpad) {
        tbl.m[nMat].src = src; tbl.m[nMat].K = K; tbl.m[nMat].Kpad = Kpad;
        tbl.m[nMat].dstOff = off;
        int r = off; off += 128 * Kpad; ++nMat; return r;
    };
    o_encn[0] = add(enc_n_W0, 12, 32);
    o_encn[1] = add(enc_n_W1, 128, 128);
    o_encn[2] = add(enc_n_W2, 128, 128);
    o_ence[0] = add(enc_e_W0, 7, 32);
    o_ence[1] = add(enc_e_W1, 128, 128);
    o_ence[2] = add(enc_e_W2, 128, 128);
    for (int s = 0; s < 3; ++s) {
        o_ge0[s] = add(gnb_e_W0 + (size_t)s * 384 * 128, 384, 384);
        o_ge1[s] = add(gnb_e_W1 + (size_t)s * 128 * 128, 128, 128);
        o_ge2[s] = add(gnb_e_W2 + (size_t)s * 128 * 128, 128, 128);
        o_gn0[s] = add(gnb_n_W0 + (size_t)s * 256 * 128, 256, 256);
        o_gn1[s] = add(gnb_n_W1 + (size_t)s * 128 * 128, 128, 128);
        o_gn2[s] = add(gnb_n_W2 + (size_t)s * 128 * 128, 128, 128);
    }
    o_dec[0] = add(dec_W0, 128, 128);
    o_dec[1] = add(dec_W1, 128, 128);

    wt_prep_kernel<<<dim3(192, 26), 256, 0, stream>>>(tbl, wt);

    if (useSorted) {
        zero_i<<<dim3((N + 255) / 256), 256, 0, stream>>>(cnt, N);
        csr_count<<<dim3((E + 255) / 256), 256, 0, stream>>>(receivers, cnt, E);
        csr_scan<<<dim3(1), 256, 0, stream>>>(cnt, cursor, N);
        csr_fill<<<dim3((E + 255) / 256), 256, 0, stream>>>(receivers, cursor, eList, E);
    }
    // zero agg once (after csr: cnt/cursor overlay agg); steps re-zero in node kernel
    zero_kernel<<<dim3((N * 32 + 255) / 256), 256, 0, stream>>>((float4*)agg, (long)N * 32);

    const dim3 gE(E / 128);                 // NW=4 edge kernels: 1250 blocks
    const dim3 gN2((N + 63) / 64);          // NW=2 node kernels: 313 blocks

    // ---- encoders ----
    gnn_mlp<2><<<gN2, 128, 0, stream>>>(wt + o_encn[0], 32, wt + o_encn[1], wt + o_encn[2],
        enc_n_b0, enc_n_b1, enc_n_b2, enc_n_g, enc_n_be,
        node_x, 12, nullptr, nullptr, nullptr, nullptr, nullptr, nullptr,
        nf, nfbf, nullptr, nullptr, N, 0, 0);
    // edge encoder gathers edge_x[eList[slot]] so ef lands in slot order
    gnn_mlp<4><<<gE, 256, 0, stream>>>(wt + o_ence[0], 32, wt + o_ence[1], wt + o_ence[2],
        enc_e_b0, enc_e_b1, enc_e_b2, enc_e_g, enc_e_be,
        edge_x, 7, nullptr, nullptr, nullptr, eL, nullptr, nullptr,
        ef, nullptr, nullptr, nullptr, E, 0, 0);

    // ---- 3 message-passing steps ----
    for (int s = 0; s < 3; ++s) {
        const float* eb0 = gnb_e_b0 + (size_t)s * 128;
        const float* eb1 = gnb_e_b1 + (size_t)s * 128;
        const float* eb2 = gnb_e_b2 + (size_t)s * 128;
        const float* eg  = gnb_e_g  + (size_t)s * 128;
        const float* ebe = gnb_e_be + (size_t)s * 128;
        const float* nb0 = gnb_n_b0 + (size_t)s * 128;
        const float* nb1 = gnb_n_b1 + (size_t)s * 128;
        const float* nb2 = gnb_n_b2 + (size_t)s * 128;
        const float* ng  = gnb_n_g  + (size_t)s * 128;
        const float* nbe = gnb_n_be + (size_t)s * 128;

        gnn_mlp<4><<<gE, 256, 0, stream>>>(wt + o_ge0[s], 384, wt + o_ge1[s], wt + o_ge2[s],
            eb0, eb1, eb2, eg, ebe,
            nullptr, 0, nfbf, ef, nullptr, eL, senders, receivers,
            ef, nullptr, agg, nullptr, E, 1, 1);
        gnn_mlp<2><<<gN2, 128, 0, stream>>>(wt + o_gn0[s], 256, wt + o_gn1[s], wt + o_gn2[s],
            nb0, nb1, nb2, ng, nbe,
            nullptr, 0, nfbf, nullptr, agg, nullptr, nullptr, nullptr,
            nf, nfbf, agg, nullptr, N, 2, 1);
    }

    // ---- decoder ----
    gnn_mlp<2><<<gN2, 128, 0, stream>>>(wt + o_dec[0], 128, wt + o_dec[1], nullptr,
        dec_b0, dec_b1, dec_b2, nullptr, nullptr,
        dec_W2, 0, nfbf, nullptr, nullptr, nullptr, nullptr, nullptr,
        nullptr, nullptr, nullptr, out, N, 3, 0);
}

// Round 14
// 654.217 us; speedup vs baseline: 1.3349x; 1.0150x over previous
//
#include <hip/hip_runtime.h>
#include <hip/hip_bf16.h>

#define NN 20000
#define EE 160000

typedef __attribute__((ext_vector_type(8))) short bf16x8;
typedef __attribute__((ext_vector_type(4))) float f32x4;

__device__ __forceinline__ unsigned short f2bf(float f) {
    unsigned int u = __float_as_uint(f);
    u += 0x7FFFu + ((u >> 16) & 1);   // RNE
    return (unsigned short)(u >> 16);
}
__device__ __forceinline__ float bf2f(short s) {
    return __uint_as_float(((unsigned int)(unsigned short)s) << 16);
}
__device__ __forceinline__ bf16x8 pack8(float4 a, float4 b) {
    bf16x8 r;
    r[0] = (short)f2bf(a.x); r[1] = (short)f2bf(a.y);
    r[2] = (short)f2bf(a.z); r[3] = (short)f2bf(a.w);
    r[4] = (short)f2bf(b.x); r[5] = (short)f2bf(b.y);
    r[6] = (short)f2bf(b.z); r[7] = (short)f2bf(b.w);
    return r;
}

#define SH_STRIDE 136
#define SW_STRIDE 56

// barrier that does NOT drain vmcnt (gathers stay in flight)
__device__ __forceinline__ void bar_lgkm() {
    asm volatile("s_waitcnt lgkmcnt(0)\n\ts_barrier" ::: "memory");
}

__device__ __forceinline__ void mfma_sweep_lds(f32x4 (&acc)[2][8], bf16x8 a0, bf16x8 a1,
                                               const short* sWb, int lm, int lq)
{
#pragma unroll
    for (int ct = 0; ct < 8; ++ct) {
        bf16x8 b = *(const bf16x8*)(sWb + (ct * 16 + lm) * SW_STRIDE + lq * 8);
        acc[0][ct] = __builtin_amdgcn_mfma_f32_16x16x32_bf16(a0, b, acc[0][ct], 0, 0, 0);
        acc[1][ct] = __builtin_amdgcn_mfma_f32_16x16x32_bf16(a1, b, acc[1][ct], 0, 0, 0);
    }
}

// W-chunk pipeline: load (registers, issued early) / store (ds_write, later).
template<int NT>
struct WStage { bf16x8 v[512 / NT]; };

template<int NT>
__device__ __forceinline__ void wload(WStage<NT>& ws, const short* __restrict__ Wt,
                                      int Kpad, int k0, int tid)
{
#pragma unroll
    for (int j = 0; j < 256 / NT; ++j) {
        int i = tid + j * NT;
        int r = i >> 1, h = i & 1;
        const short* src = Wt + (size_t)r * Kpad + k0 + h * 16;
        ws.v[2 * j]     = *(const bf16x8*)src;
        ws.v[2 * j + 1] = *(const bf16x8*)(src + 8);
    }
}
template<int NT>
__device__ __forceinline__ void wstore(const WStage<NT>& ws, short* __restrict__ sW, int tid)
{
#pragma unroll
    for (int j = 0; j < 256 / NT; ++j) {
        int i = tid + j * NT;
        int r = i >> 1, h = i & 1;
        short* dst = sW + r * SW_STRIDE + h * 16;
        *(bf16x8*)dst       = ws.v[2 * j];
        *(bf16x8*)(dst + 8) = ws.v[2 * j + 1];
    }
}

__device__ __forceinline__ void zero_acc(f32x4 (&acc)[2][8]) {
#pragma unroll
    for (int i = 0; i < 2; ++i)
#pragma unroll
        for (int j = 0; j < 8; ++j) acc[i][j] = (f32x4)(0.f);
}

__device__ __forceinline__ void park(const f32x4 (&acc)[2][8], const float* __restrict__ bias,
                                     short* __restrict__ sH, int w32, int lm, int lq)
{
#pragma unroll
    for (int ct = 0; ct < 8; ++ct) {
        float bb = bias[ct * 16 + lm];
#pragma unroll
        for (int rt = 0; rt < 2; ++rt) {
            int rbase = w32 + rt * 16 + lq * 4;
#pragma unroll
            for (int reg = 0; reg < 4; ++reg) {
                float v = fmaxf(acc[rt][ct][reg] + bb, 0.f);
                sH[(rbase + reg) * SH_STRIDE + ct * 16 + lm] = (short)f2bf(v);
            }
        }
    }
}

struct Frag {
    bf16x8 a0, a1;
    float4 f0, f1, f2, f3;
    int isF;
};

template<int MODE>
__device__ __forceinline__ void load_frag(Frag& fr, int c,
    const short* __restrict__ nfb, const float* __restrict__ eff,
    const float* __restrict__ aggf,
    int iS0, int iS1, int iR0, int iR1, size_t eO0, size_t eO1,
    int r0m, int r1m, const short* sH, int w32, int lm, int lq)
{
    int kq = lq * 8;
    fr.isF = 0;
    if (MODE == 0) {
        fr.a0 = *(const bf16x8*)&sH[(w32 + lm) * SH_STRIDE + c * 32 + kq];
        fr.a1 = *(const bf16x8*)&sH[(w32 + 16 + lm) * SH_STRIDE + c * 32 + kq];
    } else if (MODE == 1) {
        int seg = c >> 2, kb = (c & 3) * 32 + kq;
        if (seg == 0) {
            fr.a0 = *(const bf16x8*)(nfb + (size_t)iS0 * 128 + kb);
            fr.a1 = *(const bf16x8*)(nfb + (size_t)iS1 * 128 + kb);
        } else if (seg == 1) {
            fr.a0 = *(const bf16x8*)(nfb + (size_t)iR0 * 128 + kb);
            fr.a1 = *(const bf16x8*)(nfb + (size_t)iR1 * 128 + kb);
        } else {
            const float* p0 = eff + eO0 + kb;      // slot-contiguous (ef stored sorted)
            const float* p1 = eff + eO1 + kb;
            fr.f0 = *(const float4*)p0; fr.f1 = *(const float4*)(p0 + 4);
            fr.f2 = *(const float4*)p1; fr.f3 = *(const float4*)(p1 + 4);
            fr.isF = 1;
        }
    } else if (MODE == 2) {
        int seg = c >> 2, kb = (c & 3) * 32 + kq;
        if (seg == 0) {
            fr.a0 = *(const bf16x8*)(nfb + (size_t)r0m * 128 + kb);
            fr.a1 = *(const bf16x8*)(nfb + (size_t)r1m * 128 + kb);
        } else {
            const float* p0 = aggf + (size_t)r0m * 128 + kb;
            const float* p1 = aggf + (size_t)r1m * 128 + kb;
            fr.f0 = *(const float4*)p0; fr.f1 = *(const float4*)(p0 + 4);
            fr.f2 = *(const float4*)p1; fr.f3 = *(const float4*)(p1 + 4);
            fr.isF = 1;
        }
    } else {
        int kb = c * 32 + kq;
        fr.a0 = *(const bf16x8*)(nfb + (size_t)r0m * 128 + kb);
        fr.a1 = *(const bf16x8*)(nfb + (size_t)r1m * 128 + kb);
    }
}

// NW waves per block, 32 rows per wave. MODE compile-time: 0 encoder (eList =
// optional src gather map); 1 edge (sorted slots, ef slot-ordered); 2 node
// (zeroes own agg rows); 3 decoder.
template<int NW, int MODE>
__global__ __launch_bounds__(NW * 64) void gnn_mlp(
    const short* __restrict__ Wt0,
    const short* __restrict__ Wt1, const short* __restrict__ Wt2,
    const float* __restrict__ b0, const float* __restrict__ b1, const float* __restrict__ b2,
    const float* __restrict__ g, const float* __restrict__ be,
    const float* __restrict__ A0f, int K0,
    const short* __restrict__ nfb,
    const float* __restrict__ eff,
    const float* __restrict__ aggf,
    const int* __restrict__ eList,
    const int* __restrict__ senders, const int* __restrict__ receivers,
    float* __restrict__ outF, short* __restrict__ outB,
    float* __restrict__ aggOut,
    float* __restrict__ decOut,
    int M, int resid)
{
    constexpr int KP0 = (MODE == 1) ? 384 : (MODE == 2) ? 256 : (MODE == 3) ? 128 : 32;
    constexpr int nC0 = KP0 / 32;
    __shared__ short sH[NW * 32 * SH_STRIDE];
    __shared__ short sW[128 * SW_STRIDE];
    __shared__ int sRcv[NW * 32], sSnd[NW * 32];
    const int tid = threadIdx.x;
    const int lane = tid & 63;
    const int w = tid >> 6;
    const int lm = lane & 15;
    const int lq = lane >> 4;
    const int w32 = w * 32;
    const int m0 = blockIdx.x * (NW * 32);
    constexpr int NT = NW * 64;

    if (MODE == 1) {
        if (tid < NW * 32) {
            int slot = m0 + tid;                       // grid exact: slot < E
            int e = eList ? eList[slot] : slot;
            sRcv[tid] = receivers[e];
            sSnd[tid] = senders[e];
        }
        bar_lgkm();
    }

    f32x4 acc[2][8];
    zero_acc(acc);

    // -------- layer 0 (depth-2 gather pipeline, depth-1 W, lgkm barriers) ----
    if (MODE == 0) {
#pragma unroll
        for (int i = 0; i < 16; ++i) {
            int flat = lane + i * 64;
            int r = flat >> 5, k = flat & 31;
            int row = m0 + w32 + r;
            float v = 0.f;
            if (k < K0 && row < M) {
                int src = eList ? eList[row] : row;    // gather source rows (sorted write)
                v = A0f[(size_t)src * K0 + k];
            }
            sH[(w32 + r) * SH_STRIDE + k] = (short)f2bf(v);
        }
    }
    int iS0 = 0, iS1 = 0, iR0 = 0, iR1 = 0;
    size_t eO0 = 0, eO1 = 0;
    if (MODE == 1) {
        // rt-interleaved: MFMA row m of tile rt <-> sorted slot w32 + 2*m + rt.
        int s0 = w32 + 2 * lm, s1 = s0 + 1;
        iS0 = sSnd[s0]; iS1 = sSnd[s1];
        iR0 = sRcv[s0]; iR1 = sRcv[s1];
        eO0 = (size_t)(m0 + s0) * 128;                 // ef is slot-ordered: contiguous
        eO1 = (size_t)(m0 + s1) * 128;
    }
    const int r0m = min(m0 + w32 + lm, M - 1);
    const int r1m = min(m0 + w32 + 16 + lm, M - 1);

    {
        WStage<NT> ws, wsn;
        Frag cur, nx1, nx2;
        wload<NT>(ws, Wt0, KP0, 0, tid);               // W(0) before any gathers
        load_frag<MODE>(cur, 0, nfb, eff, aggf, iS0, iS1, iR0, iR1, eO0, eO1,
                        r0m, r1m, sH, w32, lm, lq);
        if (nC0 > 1)
            load_frag<MODE>(nx1, 1, nfb, eff, aggf, iS0, iS1, iR0, iR1, eO0, eO1,
                            r0m, r1m, sH, w32, lm, lq);
#pragma unroll
        for (int c = 0; c < nC0; ++c) {
            if (c + 1 < nC0)
                wload<NT>(wsn, Wt0, KP0, (c + 1) * 32, tid);
            if (c + 2 < nC0)
                load_frag<MODE>(nx2, c + 2, nfb, eff, aggf, iS0, iS1, iR0, iR1, eO0, eO1,
                                r0m, r1m, sH, w32, lm, lq);
            bar_lgkm();                 // waves done reading previous sW chunk
            wstore<NT>(ws, sW, tid);    // vmcnt targets W(c); frags c+1,c+2 + W(c+1) in flight
            bar_lgkm();                 // chunk staged
            bf16x8 u0, u1;
            if (cur.isF) { u0 = pack8(cur.f0, cur.f1); u1 = pack8(cur.f2, cur.f3); }
            else         { u0 = cur.a0;               u1 = cur.a1; }
            mfma_sweep_lds(acc, u0, u1, sW, lm, lq);
            ws = wsn; cur = nx1; nx1 = nx2;
        }
    }
    bar_lgkm();
    park(acc, b0, sH, w32, lm, lq);

    // node mode: zero this block's agg rows (all reads consumed above).
    if (MODE == 2 && aggOut) {
        int totalF4 = NW * 32 * 32;
        for (int i = tid; i < totalF4; i += NT) {
            int r = i >> 5, c4 = i & 31;
            int row = m0 + r;
            if (row < M)
                *(float4*)(aggOut + (size_t)row * 128 + c4 * 4) = make_float4(0.f, 0.f, 0.f, 0.f);
        }
    }

    // -------- layer 1 (W pipelined) --------
    zero_acc(acc);
    {
        WStage<NT> ws, wsn;
        wload<NT>(ws, Wt1, 128, 0, tid);
#pragma unroll
        for (int c = 0; c < 4; ++c) {
            if (c + 1 < 4) wload<NT>(wsn, Wt1, 128, (c + 1) * 32, tid);
            bf16x8 a0 = *(const bf16x8*)&sH[(w32 + lm) * SH_STRIDE + c * 32 + lq * 8];
            bf16x8 a1 = *(const bf16x8*)&sH[(w32 + 16 + lm) * SH_STRIDE + c * 32 + lq * 8];
            bar_lgkm();
            wstore<NT>(ws, sW, tid);
            bar_lgkm();
            mfma_sweep_lds(acc, a0, a1, sW, lm, lq);
            ws = wsn;
        }
    }
    bar_lgkm();
    park(acc, b1, sH, w32, lm, lq);

    // -------- decoder tail --------
    if (MODE == 3) {
#pragma unroll
        for (int t = 0; t < 2; ++t) {
            int idx = t * 64 + lane;
            if (idx < 96) {
                int r = idx / 3, o = idx - r * 3;
                int row = m0 + w32 + r;
                if (row < M) {
                    float s = b2[o];
#pragma unroll
                    for (int kk = 0; kk < 16; ++kk) {
                        bf16x8 h8 = *(const bf16x8*)&sH[(w32 + r) * SH_STRIDE + kk * 8];
#pragma unroll
                        for (int j = 0; j < 8; ++j)
                            s += bf2f(h8[j]) * A0f[(kk * 8 + j) * 3 + o];
                    }
                    decOut[(size_t)row * 3 + o] = s;
                }
            }
        }
        return;
    }

    // -------- layer 2 (W pipelined) --------
    zero_acc(acc);
    {
        WStage<NT> ws, wsn;
        wload<NT>(ws, Wt2, 128, 0, tid);
#pragma unroll
        for (int c = 0; c < 4; ++c) {
            if (c + 1 < 4) wload<NT>(wsn, Wt2, 128, (c + 1) * 32, tid);
            bf16x8 a0 = *(const bf16x8*)&sH[(w32 + lm) * SH_STRIDE + c * 32 + lq * 8];
            bf16x8 a1 = *(const bf16x8*)&sH[(w32 + 16 + lm) * SH_STRIDE + c * 32 + lq * 8];
            bar_lgkm();
            wstore<NT>(ws, sW, tid);
            bar_lgkm();
            mfma_sweep_lds(acc, a0, a1, sW, lm, lq);
            ws = wsn;
        }
    }

    // -------- epilogue --------
    float g_[8], be_[8], b2_[8];
#pragma unroll
    for (int ct = 0; ct < 8; ++ct) {
        g_[ct] = g[ct * 16 + lm]; be_[ct] = be[ct * 16 + lm]; b2_[ct] = b2[ct * 16 + lm];
    }

    if (MODE == 1) {
        // lane's 8 C-rows are 8 CONSECUTIVE sorted slots: one merge run;
        // ef residual written at slot position (contiguous stream)
        float run[8];
        int curRcv = -1;
#pragma unroll
        for (int j = 0; j < 8; ++j) {
            int rt = j & 1, reg = j >> 1;
            int rloc = w32 + lq * 8 + j;
            float v[8];
            float s = 0.f;
#pragma unroll
            for (int ct = 0; ct < 8; ++ct) { v[ct] = acc[rt][ct][reg] + b2_[ct]; s += v[ct]; }
            s += __shfl_xor(s, 1); s += __shfl_xor(s, 2);
            s += __shfl_xor(s, 4); s += __shfl_xor(s, 8);
            float mu = s * (1.f / 128.f);
            float q = 0.f;
#pragma unroll
            for (int ct = 0; ct < 8; ++ct) { v[ct] -= mu; q += v[ct] * v[ct]; }
            q += __shfl_xor(q, 1); q += __shfl_xor(q, 2);
            q += __shfl_xor(q, 4); q += __shfl_xor(q, 8);
            float rs = rsqrtf(q * (1.f / 128.f) + 1e-5f);
            int rcv = sRcv[rloc];
            float o[8];
#pragma unroll
            for (int ct = 0; ct < 8; ++ct) {
                o[ct] = v[ct] * rs * g_[ct] + be_[ct];
                size_t gi = (size_t)(m0 + rloc) * 128 + ct * 16 + lm;
                outF[gi] += o[ct];                      // ef residual, slot-ordered
            }
            if (rcv != curRcv) {
                if (curRcv >= 0) {
#pragma unroll
                    for (int ct = 0; ct < 8; ++ct)
                        atomicAdd(aggOut + (size_t)curRcv * 128 + ct * 16 + lm, run[ct]);
                }
                curRcv = rcv;
#pragma unroll
                for (int ct = 0; ct < 8; ++ct) run[ct] = o[ct];
            } else {
#pragma unroll
                for (int ct = 0; ct < 8; ++ct) run[ct] += o[ct];
            }
        }
        if (curRcv >= 0) {
#pragma unroll
            for (int ct = 0; ct < 8; ++ct)
                atomicAdd(aggOut + (size_t)curRcv * 128 + ct * 16 + lm, run[ct]);
        }
    } else {
#pragma unroll
        for (int rt = 0; rt < 2; ++rt) {
#pragma unroll
            for (int reg = 0; reg < 4; ++reg) {
                int row = m0 + w32 + rt * 16 + lq * 4 + reg;
                float v[8];
                float s = 0.f;
#pragma unroll
                for (int ct = 0; ct < 8; ++ct) { v[ct] = acc[rt][ct][reg] + b2_[ct]; s += v[ct]; }
                s += __shfl_xor(s, 1); s += __shfl_xor(s, 2);
                s += __shfl_xor(s, 4); s += __shfl_xor(s, 8);
                float mu = s * (1.f / 128.f);
                float q = 0.f;
#pragma unroll
                for (int ct = 0; ct < 8; ++ct) { v[ct] -= mu; q += v[ct] * v[ct]; }
                q += __shfl_xor(q, 1); q += __shfl_xor(q, 2);
                q += __shfl_xor(q, 4); q += __shfl_xor(q, 8);
                float rs = rsqrtf(q * (1.f / 128.f) + 1e-5f);
                if (row < M) {
#pragma unroll
                    for (int ct = 0; ct < 8; ++ct) {
                        float o = v[ct] * rs * g_[ct] + be_[ct];
                        size_t gi = (size_t)row * 128 + ct * 16 + lm;
                        if (resid) {
                            float ns = outF[gi] + o;
                            outF[gi] = ns;
                            if (outB) outB[gi] = (short)f2bf(ns);
                        } else {
                            outF[gi] = o;
                            if (outB) outB[gi] = (short)f2bf(o);
                        }
                    }
                }
            }
        }
    }
}

// ---------------------------------------------------------------------------
__global__ void zero_i(int* __restrict__ p, int n)
{
    int i = blockIdx.x * 256 + threadIdx.x;
    if (i < n) p[i] = 0;
}
__global__ void csr_count(const int* __restrict__ recv, int* __restrict__ cnt, int E)
{
    int i = blockIdx.x * 256 + threadIdx.x;
    if (i < E) atomicAdd(&cnt[recv[i]], 1);
}
__global__ __launch_bounds__(256) void csr_scan(const int* __restrict__ cnt,
                                                int* __restrict__ cursor, int N)
{
    __shared__ int ssum[257];
    const int tid = threadIdx.x;
    const int per = (N + 255) / 256;
    const int lo = tid * per, hi = min(lo + per, N);
    int s = 0;
    for (int i = lo; i < hi; ++i) s += cnt[i];
    ssum[tid] = s;
    __syncthreads();
    if (tid == 0) {
        int run = 0;
        for (int i = 0; i < 256; ++i) { int t = ssum[i]; ssum[i] = run; run += t; }
        ssum[256] = run;
    }
    __syncthreads();
    int run = ssum[tid];
    for (int i = lo; i < hi; ++i) { int c = cnt[i]; cursor[i] = run; run += c; }
}
__global__ void csr_fill(const int* __restrict__ recv, int* __restrict__ cursor,
                         int* __restrict__ eList, int E)
{
    int i = blockIdx.x * 256 + threadIdx.x;
    if (i < E) {
        int pos = atomicAdd(&cursor[recv[i]], 1);
        eList[pos] = i;
    }
}

// ---------------------------------------------------------------------------
struct WtPrep { const float* src; int K; int Kpad; int dstOff; };
struct WtPrepAll { WtPrep m[26]; };

__global__ void wt_prep_kernel(WtPrepAll all, short* __restrict__ dst)
{
    const WtPrep p = all.m[blockIdx.y];
    int total = 128 * p.Kpad;
    int idx = blockIdx.x * 256 + threadIdx.x;
    if (idx >= total) return;
    int n = idx / p.Kpad, k = idx - n * p.Kpad;
    float v = (k < p.K) ? p.src[(size_t)k * 128 + n] : 0.f;
    dst[p.dstOff + idx] = (short)f2bf(v);
}

__global__ void zero_kernel(float4* __restrict__ p, long n4)
{
    long i = (long)blockIdx.x * blockDim.x + threadIdx.x;
    if (i < n4) p[i] = make_float4(0.f, 0.f, 0.f, 0.f);
}

// ---------------------------------------------------------------------------
extern "C" void kernel_launch(void* const* d_in, const int* in_sizes, int n_in,
                              void* d_out, int out_size, void* d_ws, size_t ws_size,
                              hipStream_t stream)
{
    const float* node_x   = (const float*)d_in[0];
    const float* edge_x   = (const float*)d_in[1];
    const float* enc_n_W0 = (const float*)d_in[2];
    const float* enc_n_b0 = (const float*)d_in[3];
    const float* enc_n_W1 = (const float*)d_in[4];
    const float* enc_n_b1 = (const float*)d_in[5];
    const float* enc_n_W2 = (const float*)d_in[6];
    const float* enc_n_b2 = (const float*)d_in[7];
    const float* enc_n_g  = (const float*)d_in[8];
    const float* enc_n_be = (const float*)d_in[9];
    const float* enc_e_W0 = (const float*)d_in[10];
    const float* enc_e_b0 = (const float*)d_in[11];
    const float* enc_e_W1 = (const float*)d_in[12];
    const float* enc_e_b1 = (const float*)d_in[13];
    const float* enc_e_W2 = (const float*)d_in[14];
    const float* enc_e_b2 = (const float*)d_in[15];
    const float* enc_e_g  = (const float*)d_in[16];
    const float* enc_e_be = (const float*)d_in[17];
    const float* gnb_e_W0 = (const float*)d_in[18];
    const float* gnb_e_b0 = (const float*)d_in[19];
    const float* gnb_e_W1 = (const float*)d_in[20];
    const float* gnb_e_b1 = (const float*)d_in[21];
    const float* gnb_e_W2 = (const float*)d_in[22];
    const float* gnb_e_b2 = (const float*)d_in[23];
    const float* gnb_e_g  = (const float*)d_in[24];
    const float* gnb_e_be = (const float*)d_in[25];
    const float* gnb_n_W0 = (const float*)d_in[26];
    const float* gnb_n_b0 = (const float*)d_in[27];
    const float* gnb_n_W1 = (const float*)d_in[28];
    const float* gnb_n_b1 = (const float*)d_in[29];
    const float* gnb_n_W2 = (const float*)d_in[30];
    const float* gnb_n_b2 = (const float*)d_in[31];
    const float* gnb_n_g  = (const float*)d_in[32];
    const float* gnb_n_be = (const float*)d_in[33];
    const float* dec_W0   = (const float*)d_in[34];
    const float* dec_b0   = (const float*)d_in[35];
    const float* dec_W1   = (const float*)d_in[36];
    const float* dec_b1   = (const float*)d_in[37];
    const float* dec_W2   = (const float*)d_in[38];
    const float* dec_b2   = (const float*)d_in[39];
    const int*   senders  = (const int*)d_in[40];
    const int*   receivers= (const int*)d_in[41];
    float* out = (float*)d_out;

    const int N = NN, E = EE;
    const int WT_TOTAL = (32 + 128 + 128 + 32 + 128 + 128 + 3 * (384 + 128 + 128 + 256 + 128 + 128)
                          + 128 + 128) * 128;

    // ---- workspace layout: identical to rounds 6..13 (109.26 MB, known-good) ----
    float* nf   = (float*)d_ws;
    float* agg  = nf + (size_t)N * 128;
    float* ef   = agg + (size_t)N * 128;     // stored in SORTED-SLOT order
    short* nfbf = (short*)(ef + (size_t)E * 128);
    short* wt   = nfbf + (size_t)N * 128;
    int*   eList = (int*)(wt + WT_TOTAL);
    size_t need_sorted = (size_t)((char*)(eList + E) - (char*)d_ws);
    int* cnt    = (int*)agg;
    int* cursor = cnt + N;

    const bool useSorted = (ws_size >= need_sorted);
    const int* eL = useSorted ? eList : nullptr;

    WtPrepAll tbl;
    int nMat = 0, off = 0;
    int o_encn[3], o_ence[3], o_ge0[3], o_ge1[3], o_ge2[3], o_gn0[3], o_gn1[3], o_gn2[3], o_dec[2];
    auto add = [&](const float* src, int K, int Kpad) {
        tbl.m[nMat].src = src; tbl.m[nMat].K = K; tbl.m[nMat].Kpad = Kpad;
        tbl.m[nMat].dstOff = off;
        int r = off; off += 128 * Kpad; ++nMat; return r;
    };
    o_encn[0] = add(enc_n_W0, 12, 32);
    o_encn[1] = add(enc_n_W1, 128, 128);
    o_encn[2] = add(enc_n_W2, 128, 128);
    o_ence[0] = add(enc_e_W0, 7, 32);
    o_ence[1] = add(enc_e_W1, 128, 128);
    o_ence[2] = add(enc_e_W2, 128, 128);
    for (int s = 0; s < 3; ++s) {
        o_ge0[s] = add(gnb_e_W0 + (size_t)s * 384 * 128, 384, 384);
        o_ge1[s] = add(gnb_e_W1 + (size_t)s * 128 * 128, 128, 128);
        o_ge2[s] = add(gnb_e_W2 + (size_t)s * 128 * 128, 128, 128);
        o_gn0[s] = add(gnb_n_W0 + (size_t)s * 256 * 128, 256, 256);
        o_gn1[s] = add(gnb_n_W1 + (size_t)s * 128 * 128, 128, 128);
        o_gn2[s] = add(gnb_n_W2 + (size_t)s * 128 * 128, 128, 128);
    }
    o_dec[0] = add(dec_W0, 128, 128);
    o_dec[1] = add(dec_W1, 128, 128);

    wt_prep_kernel<<<dim3(192, 26), 256, 0, stream>>>(tbl, wt);

    if (useSorted) {
        zero_i<<<dim3((N + 255) / 256), 256, 0, stream>>>(cnt, N);
        csr_count<<<dim3((E + 255) / 256), 256, 0, stream>>>(receivers, cnt, E);
        csr_scan<<<dim3(1), 256, 0, stream>>>(cnt, cursor, N);
        csr_fill<<<dim3((E + 255) / 256), 256, 0, stream>>>(receivers, cursor, eList, E);
    }
    // zero agg once (after csr: cnt/cursor overlay agg); steps re-zero in node kernel
    zero_kernel<<<dim3((N * 32 + 255) / 256), 256, 0, stream>>>((float4*)agg, (long)N * 32);

    const dim3 gE(E / 128);                 // NW=4 edge kernels: 1250 blocks
    const dim3 gN2((N + 63) / 64);          // NW=2 node kernels: 313 blocks

    // ---- encoders ----
    gnn_mlp<2, 0><<<gN2, 128, 0, stream>>>(wt + o_encn[0], wt + o_encn[1], wt + o_encn[2],
        enc_n_b0, enc_n_b1, enc_n_b2, enc_n_g, enc_n_be,
        node_x, 12, nullptr, nullptr, nullptr, nullptr, nullptr, nullptr,
        nf, nfbf, nullptr, nullptr, N, 0);
    // edge encoder gathers edge_x[eList[slot]] so ef lands in slot order
    gnn_mlp<4, 0><<<gE, 256, 0, stream>>>(wt + o_ence[0], wt + o_ence[1], wt + o_ence[2],
        enc_e_b0, enc_e_b1, enc_e_b2, enc_e_g, enc_e_be,
        edge_x, 7, nullptr, nullptr, nullptr, eL, nullptr, nullptr,
        ef, nullptr, nullptr, nullptr, E, 0);

    // ---- 3 message-passing steps ----
    for (int s = 0; s < 3; ++s) {
        const float* eb0 = gnb_e_b0 + (size_t)s * 128;
        const float* eb1 = gnb_e_b1 + (size_t)s * 128;
        const float* eb2 = gnb_e_b2 + (size_t)s * 128;
        const float* eg  = gnb_e_g  + (size_t)s * 128;
        const float* ebe = gnb_e_be + (size_t)s * 128;
        const float* nb0 = gnb_n_b0 + (size_t)s * 128;
        const float* nb1 = gnb_n_b1 + (size_t)s * 128;
        const float* nb2 = gnb_n_b2 + (size_t)s * 128;
        const float* ng  = gnb_n_g  + (size_t)s * 128;
        const float* nbe = gnb_n_be + (size_t)s * 128;

        gnn_mlp<4, 1><<<gE, 256, 0, stream>>>(wt + o_ge0[s], wt + o_ge1[s], wt + o_ge2[s],
            eb0, eb1, eb2, eg, ebe,
            nullptr, 0, nfbf, ef, nullptr, eL, senders, receivers,
            ef, nullptr, agg, nullptr, E, 1);
        gnn_mlp<2, 2><<<gN2, 128, 0, stream>>>(wt + o_gn0[s], wt + o_gn1[s], wt + o_gn2[s],
            nb0, nb1, nb2, ng, nbe,
            nullptr, 0, nfbf, nullptr, agg, nullptr, nullptr, nullptr,
            nf, nfbf, agg, nullptr, N, 1);
    }

    // ---- decoder ----
    gnn_mlp<2, 3><<<gN2, 128, 0, stream>>>(wt + o_dec[0], wt + o_dec[1], nullptr,
        dec_b0, dec_b1, dec_b2, nullptr, nullptr,
        dec_W2, 0, nfbf, nullptr, nullptr, nullptr, nullptr, nullptr,
        nullptr, nullptr, nullptr, out, N, 0);
}